// Round 1
// baseline (540.301 us; speedup 1.0000x reference)
//
#include <hip/hip_runtime.h>
#include <stdint.h>

#define K_DIM 1024
#define B_SZ 4
#define N_SEQ 2048
#define HEADS 16
#define DH 64
#define M_TOT (B_SZ * N_SEQ)  // 8192

typedef __bf16 bf16x8 __attribute__((ext_vector_type(8)));
typedef float f32x4 __attribute__((ext_vector_type(4)));

typedef const uint32_t __attribute__((address_space(1))) gas_u32;
typedef uint32_t __attribute__((address_space(3))) las_u32;

__device__ __forceinline__ uint16_t f2bf(float f) {
  uint32_t u = __float_as_uint(f);
  u += 0x7FFFu + ((u >> 16) & 1u);  // round-nearest-even
  return (uint16_t)(u >> 16);
}

// async global->LDS, 16B per lane; LDS dest = base + lane*16 (wave-uniform base)
__device__ __forceinline__ void gld_lds16(const uint16_t* g, uint16_t* lds) {
  __builtin_amdgcn_global_load_lds((gas_u32*)g, (las_u32*)lds, 16, 0, 0);
}

// ---------------- fp32 -> bf16 convert ----------------
__global__ __launch_bounds__(256) void conv_bf16_k(const float* __restrict__ src,
                                                   uint16_t* __restrict__ dst, int n4) {
  int i = blockIdx.x * blockDim.x + threadIdx.x;
  if (i < n4) {
    float4 v = ((const float4*)src)[i];
    ushort4 o;
    o.x = f2bf(v.x); o.y = f2bf(v.y); o.z = f2bf(v.z); o.w = f2bf(v.w);
    ((ushort4*)dst)[i] = o;
  }
}

// ---------------- transpose + convert weights: dst[n][k] = src[k][n] ----------------
__global__ __launch_bounds__(256) void transpose_conv(const float* __restrict__ src,
                                                      uint16_t* __restrict__ dst) {
  __shared__ float tile[32][33];
  const int tx = threadIdx.x, ty = threadIdx.y;
  const int bx = blockIdx.x * 32, by = blockIdx.y * 32;
#pragma unroll
  for (int i = 0; i < 32; i += 8)
    tile[ty + i][tx] = src[(size_t)(by + ty + i) * 1024 + bx + tx];
  __syncthreads();
#pragma unroll
  for (int i = 0; i < 32; i += 8)
    dst[(size_t)(bx + ty + i) * 1024 + by + tx] = f2bf(tile[tx][ty + i]);
}

// ---------------- GEMM: C[M,1024] = A[M,1024] @ B[1024,1024], BT[n][k] given ----------------
// MODE 0: bf16 out in [B,H,N,Dh] head-split layout.  MODE 1: fp32 out row-major + bias.
template <int MODE>
__global__ __launch_bounds__(256, 2) void gemm_bf16(const uint16_t* __restrict__ A,
                                                    const uint16_t* __restrict__ BT,
                                                    void* __restrict__ Cout,
                                                    const float* __restrict__ bias) {
  __shared__ __align__(16) uint16_t As[128 * 32];
  __shared__ __align__(16) uint16_t Bs[128 * 32];
  const int tid = threadIdx.x;
  const int wave = tid >> 6, lane = tid & 63;
  const int g = lane >> 4, c16 = lane & 15;
  const int m0 = blockIdx.y * 128, n0 = blockIdx.x * 128;
  const int wr = wave >> 1, wc = wave & 1;

  const f32x4 fzero = {0.f, 0.f, 0.f, 0.f};
  f32x4 acc[4][4];
#pragma unroll
  for (int i = 0; i < 4; ++i)
#pragma unroll
    for (int j = 0; j < 4; ++j) acc[i][j] = fzero;

  // staging: wave covers 32 rows via 2 calls of 16 rows; lane -> row l/4, col (l%4)*8
  const int srow = wave * 32 + (lane >> 2);
  const int scol = (lane & 3) * 8;
  const uint16_t* ag0 = A + (size_t)(m0 + srow) * K_DIM + scol;
  const uint16_t* ag1 = A + (size_t)(m0 + srow + 16) * K_DIM + scol;
  const uint16_t* bg0 = BT + (size_t)(n0 + srow) * K_DIM + scol;
  const uint16_t* bg1 = BT + (size_t)(n0 + srow + 16) * K_DIM + scol;
  uint16_t* la0 = &As[(wave * 32) * 32];
  uint16_t* la1 = &As[(wave * 32 + 16) * 32];
  uint16_t* lb0 = &Bs[(wave * 32) * 32];
  uint16_t* lb1 = &Bs[(wave * 32 + 16) * 32];

  for (int kt = 0; kt < K_DIM / 32; ++kt) {
    __syncthreads();
    gld_lds16(ag0 + kt * 32, la0);
    gld_lds16(ag1 + kt * 32, la1);
    gld_lds16(bg0 + kt * 32, lb0);
    gld_lds16(bg1 + kt * 32, lb1);
    __syncthreads();
    bf16x8 avec[4], bvec[4];
#pragma unroll
    for (int i = 0; i < 4; ++i)
      avec[i] = *(const bf16x8*)&As[(wr * 64 + i * 16 + c16) * 32 + g * 8];
#pragma unroll
    for (int j = 0; j < 4; ++j)
      bvec[j] = *(const bf16x8*)&Bs[(wc * 64 + j * 16 + c16) * 32 + g * 8];
#pragma unroll
    for (int i = 0; i < 4; ++i)
#pragma unroll
      for (int j = 0; j < 4; ++j)
        acc[i][j] = __builtin_amdgcn_mfma_f32_16x16x32_bf16(avec[i], bvec[j], acc[i][j], 0, 0, 0);
  }

#pragma unroll
  for (int i = 0; i < 4; ++i) {
#pragma unroll
    for (int j = 0; j < 4; ++j) {
      const int col = n0 + wc * 64 + j * 16 + c16;
#pragma unroll
      for (int r = 0; r < 4; ++r) {
        const int row = m0 + wr * 64 + i * 16 + g * 4 + r;
        if (MODE == 0) {
          const int b = row >> 11, n = row & 2047;
          const int h = col >> 6, d = col & 63;
          ((uint16_t*)Cout)[(((size_t)(b * HEADS + h)) * N_SEQ + n) * DH + d] = f2bf(acc[i][j][r]);
        } else {
          ((float*)Cout)[(size_t)row * 1024 + col] = acc[i][j][r] + bias[col];
        }
      }
    }
  }
}

// ---------------- flash attention: 64-row Q tile, 64-key tiles ----------------
__global__ __launch_bounds__(256, 2) void attention_k(const uint16_t* __restrict__ qm,
                                                      const uint16_t* __restrict__ km,
                                                      const uint16_t* __restrict__ vm,
                                                      uint16_t* __restrict__ om) {
  __shared__ __align__(16) uint16_t Ks[64 * 72];
  __shared__ __align__(16) uint16_t Vts[64 * 72];
  __shared__ __align__(16) uint16_t Ps[64 * 72];
  const int tid = threadIdx.x;
  const int wave = tid >> 6, lane = tid & 63;
  const int g = lane >> 4, c16 = lane & 15;
  const int bh = blockIdx.y;
  const int b = bh >> 4, h = bh & 15;
  const int q0 = blockIdx.x * 64;

  const uint16_t* qbase = qm + (size_t)bh * N_SEQ * DH;
  const uint16_t* kbase = km + (size_t)bh * N_SEQ * DH;
  const uint16_t* vbase = vm + (size_t)bh * N_SEQ * DH;

  // Q A-fragments direct from global: rows wave*16 + c16, k = g*8 (+32)
  bf16x8 qf0, qf1;
  {
    const uint16_t* qp = qbase + (size_t)(q0 + wave * 16 + c16) * DH + g * 8;
    qf0 = *(const bf16x8*)qp;
    qf1 = *(const bf16x8*)(qp + 32);
  }

  const f32x4 fzero = {0.f, 0.f, 0.f, 0.f};
  float m_run[4], l_run[4];
  f32x4 oacc[4];
#pragma unroll
  for (int r = 0; r < 4; ++r) { m_run[r] = -1e30f; l_run[r] = 0.f; }
#pragma unroll
  for (int jt = 0; jt < 4; ++jt) oacc[jt] = fzero;

  const int vkey = tid & 63, vdg = tid >> 6;

  for (int t = 0; t < N_SEQ / 64; ++t) {
    __syncthreads();
    // stage K tile (contiguous 64x64 bf16) into padded LDS rows
#pragma unroll
    for (int p = 0; p < 2; ++p) {
      int e = (p * 256 + tid) * 8;
      int row = e >> 6, col = e & 63;
      *(uint4*)&Ks[row * 72 + col] = *(const uint4*)&kbase[(size_t)t * 64 * DH + e];
    }
    // stage V transposed: Vts[d][key]
    {
      const uint16_t* vp = vbase + (size_t)(t * 64 + vkey) * DH + vdg * 16;
      uint4 t0 = *(const uint4*)vp;
      uint4 t1 = *(const uint4*)(vp + 8);
      uint32_t w[8] = {t0.x, t0.y, t0.z, t0.w, t1.x, t1.y, t1.z, t1.w};
#pragma unroll
      for (int i = 0; i < 8; ++i) {
        Vts[(vdg * 16 + 2 * i) * 72 + vkey] = (uint16_t)w[i];
        Vts[(vdg * 16 + 2 * i + 1) * 72 + vkey] = (uint16_t)(w[i] >> 16);
      }
    }
    __syncthreads();

    // S = Q @ K^T for this wave's 16 q-rows x 64 keys
    f32x4 s[4];
#pragma unroll
    for (int kt = 0; kt < 4; ++kt) {
      bf16x8 kf0 = *(const bf16x8*)&Ks[(kt * 16 + c16) * 72 + g * 8];
      bf16x8 kf1 = *(const bf16x8*)&Ks[(kt * 16 + c16) * 72 + 32 + g * 8];
      f32x4 z = fzero;
      z = __builtin_amdgcn_mfma_f32_16x16x32_bf16(qf0, kf0, z, 0, 0, 0);
      z = __builtin_amdgcn_mfma_f32_16x16x32_bf16(qf1, kf1, z, 0, 0, 0);
      s[kt] = z;
    }

    // online softmax (per lane: 4 rows, cols kt*16 + c16)
#pragma unroll
    for (int r = 0; r < 4; ++r) {
      float v0 = s[0][r] * 0.125f, v1 = s[1][r] * 0.125f;
      float v2 = s[2][r] * 0.125f, v3 = s[3][r] * 0.125f;
      float mt = fmaxf(fmaxf(v0, v1), fmaxf(v2, v3));
#pragma unroll
      for (int off = 1; off < 16; off <<= 1) mt = fmaxf(mt, __shfl_xor(mt, off));
      float mnew = fmaxf(m_run[r], mt);
      float p0 = __expf(v0 - mnew), p1 = __expf(v1 - mnew);
      float p2 = __expf(v2 - mnew), p3 = __expf(v3 - mnew);
      float rs = p0 + p1 + p2 + p3;
#pragma unroll
      for (int off = 1; off < 16; off <<= 1) rs += __shfl_xor(rs, off);
      float alpha = __expf(m_run[r] - mnew);
      l_run[r] = l_run[r] * alpha + rs;
      m_run[r] = mnew;
#pragma unroll
      for (int jt = 0; jt < 4; ++jt) oacc[jt][r] *= alpha;
      int prow = (wave * 16 + g * 4 + r) * 72 + c16;
      Ps[prow + 0] = f2bf(p0);
      Ps[prow + 16] = f2bf(p1);
      Ps[prow + 32] = f2bf(p2);
      Ps[prow + 48] = f2bf(p3);
    }

    // O += P @ V  (P write/read same-wave only: DS pipe is in-order, no barrier needed)
    bf16x8 pa0 = *(const bf16x8*)&Ps[(wave * 16 + c16) * 72 + g * 8];
    bf16x8 pa1 = *(const bf16x8*)&Ps[(wave * 16 + c16) * 72 + 32 + g * 8];
#pragma unroll
    for (int jt = 0; jt < 4; ++jt) {
      bf16x8 vb0 = *(const bf16x8*)&Vts[(jt * 16 + c16) * 72 + g * 8];
      bf16x8 vb1 = *(const bf16x8*)&Vts[(jt * 16 + c16) * 72 + 32 + g * 8];
      oacc[jt] = __builtin_amdgcn_mfma_f32_16x16x32_bf16(pa0, vb0, oacc[jt], 0, 0, 0);
      oacc[jt] = __builtin_amdgcn_mfma_f32_16x16x32_bf16(pa1, vb1, oacc[jt], 0, 0, 0);
    }
  }

  // normalize + write O in [B][N][H*Dh] bf16 layout
#pragma unroll
  for (int r = 0; r < 4; ++r) {
    float inv = 1.f / l_run[r];
    int row = q0 + wave * 16 + g * 4 + r;
#pragma unroll
    for (int jt = 0; jt < 4; ++jt) {
      int col = h * DH + jt * 16 + c16;
      om[((size_t)b * N_SEQ + row) * 1024 + col] = f2bf(oacc[jt][r] * inv);
    }
  }
}

// ---------------- LayerNorm + residual ----------------
__global__ __launch_bounds__(256) void ln_res_k(const float* __restrict__ proj,
                                                const float* __restrict__ query,
                                                const float* __restrict__ gamma,
                                                const float* __restrict__ beta,
                                                float* __restrict__ out) {
  const int row = blockIdx.x;
  const int tid = threadIdx.x;
  const size_t base = (size_t)row * 1024 + tid * 4;
  float4 v = *(const float4*)(proj + base);
  float s = v.x + v.y + v.z + v.w;
  float s2 = v.x * v.x + v.y * v.y + v.z * v.z + v.w * v.w;
#pragma unroll
  for (int off = 1; off < 64; off <<= 1) {
    s += __shfl_xor(s, off);
    s2 += __shfl_xor(s2, off);
  }
  __shared__ float red[8];
  const int wave = tid >> 6, lane = tid & 63;
  if (lane == 0) { red[wave] = s; red[4 + wave] = s2; }
  __syncthreads();
  s = red[0] + red[1] + red[2] + red[3];
  s2 = red[4] + red[5] + red[6] + red[7];
  const float mu = s * (1.f / 1024.f);
  const float var = fmaxf(s2 * (1.f / 1024.f) - mu * mu, 0.f);
  const float rstd = rsqrtf(var + 1e-5f);
  float4 gq = *(const float4*)(gamma + tid * 4);
  float4 bq = *(const float4*)(beta + tid * 4);
  float4 qq = *(const float4*)(query + base);
  float4 o;
  o.x = (v.x - mu) * rstd * gq.x + bq.x + qq.x;
  o.y = (v.y - mu) * rstd * gq.y + bq.y + qq.y;
  o.z = (v.z - mu) * rstd * gq.z + bq.z + qq.z;
  o.w = (v.w - mu) * rstd * gq.w + bq.w + qq.w;
  *(float4*)(out + base) = o;
}

extern "C" void kernel_launch(void* const* d_in, const int* in_sizes, int n_in,
                              void* d_out, int out_size, void* d_ws, size_t ws_size,
                              hipStream_t stream) {
  (void)in_sizes; (void)n_in; (void)out_size; (void)ws_size;
  const float* query = (const float*)d_in[0];
  const float* key_ = (const float*)d_in[1];
  const float* value = (const float*)d_in[2];
  const float* Wq = (const float*)d_in[3];
  const float* Wk = (const float*)d_in[4];
  const float* Wv = (const float*)d_in[5];
  const float* Wo = (const float*)d_in[6];
  const float* bo = (const float*)d_in[7];
  const float* gamma = (const float*)d_in[8];
  const float* beta = (const float*)d_in[9];
  float* out = (float*)d_out;

  const size_t NELEM = (size_t)M_TOT * 1024;  // 8388608
  uint16_t* wsp = (uint16_t*)d_ws;
  uint16_t* WqT = wsp;
  uint16_t* WkT = WqT + 1024 * 1024;
  uint16_t* WvT = WkT + 1024 * 1024;
  uint16_t* WoT = WvT + 1024 * 1024;
  uint16_t* xq = WoT + 1024 * 1024;
  uint16_t* xk = xq + NELEM;
  uint16_t* xv = xk + NELEM;
  uint16_t* qb = xv + NELEM;
  uint16_t* kb = qb + NELEM;
  uint16_t* vb = kb + NELEM;
  uint16_t* attnO = xq;      // alias: xq dead after GEMM-q
  float* proj = (float*)xk;  // alias: xk+xv dead after GEMM-k/v (exactly 32MB)

  const int n4 = (int)(NELEM / 4);
  conv_bf16_k<<<8192, 256, 0, stream>>>(query, xq, n4);
  conv_bf16_k<<<8192, 256, 0, stream>>>(key_, xk, n4);
  conv_bf16_k<<<8192, 256, 0, stream>>>(value, xv, n4);

  dim3 tb(32, 8);
  transpose_conv<<<dim3(32, 32), tb, 0, stream>>>(Wq, WqT);
  transpose_conv<<<dim3(32, 32), tb, 0, stream>>>(Wk, WkT);
  transpose_conv<<<dim3(32, 32), tb, 0, stream>>>(Wv, WvT);
  transpose_conv<<<dim3(32, 32), tb, 0, stream>>>(Wo, WoT);

  dim3 gg(8, 64);
  gemm_bf16<0><<<gg, 256, 0, stream>>>(xq, WqT, qb, nullptr);
  gemm_bf16<0><<<gg, 256, 0, stream>>>(xk, WkT, kb, nullptr);
  gemm_bf16<0><<<gg, 256, 0, stream>>>(xv, WvT, vb, nullptr);

  attention_k<<<dim3(32, 64), 256, 0, stream>>>(qb, kb, vb, attnO);

  gemm_bf16<1><<<gg, 256, 0, stream>>>(attnO, WoT, proj, bo);

  ln_res_k<<<8192, 256, 0, stream>>>(proj, query, gamma, beta, out);
}

// Round 2
// 391.235 us; speedup vs baseline: 1.3810x; 1.3810x over previous
//
#include <hip/hip_runtime.h>
#include <stdint.h>

#define K_DIM 1024
#define B_SZ 4
#define N_SEQ 2048
#define HEADS 16
#define DH 64
#define M_TOT (B_SZ * N_SEQ)  // 8192

typedef __bf16 bf16x8 __attribute__((ext_vector_type(8)));
typedef __bf16 bf16x4 __attribute__((ext_vector_type(4)));
typedef float f32x4 __attribute__((ext_vector_type(4)));

typedef const uint32_t __attribute__((address_space(1))) gas_u32;
typedef uint32_t __attribute__((address_space(3))) las_u32;

__device__ __forceinline__ uint16_t f2bf(float f) {
  uint32_t u = __float_as_uint(f);
  u += 0x7FFFu + ((u >> 16) & 1u);  // round-nearest-even
  return (uint16_t)(u >> 16);
}

// async global->LDS, 16B per lane; LDS dest = base + lane*16 (wave-uniform base)
__device__ __forceinline__ void gld_lds16(const uint16_t* g, uint16_t* lds) {
  __builtin_amdgcn_global_load_lds((gas_u32*)g, (las_u32*)lds, 16, 0, 0);
}

// ---------------- fp32 -> bf16 convert ----------------
__global__ __launch_bounds__(256) void conv_bf16_k(const float* __restrict__ src,
                                                   uint16_t* __restrict__ dst, int n4) {
  int i = blockIdx.x * blockDim.x + threadIdx.x;
  if (i < n4) {
    float4 v = ((const float4*)src)[i];
    ushort4 o;
    o.x = f2bf(v.x); o.y = f2bf(v.y); o.z = f2bf(v.z); o.w = f2bf(v.w);
    ((ushort4*)dst)[i] = o;
  }
}

// ---------------- transpose + convert weights: dst[n][k] = src[k][n] ----------------
__global__ __launch_bounds__(256) void transpose_conv(const float* __restrict__ src,
                                                      uint16_t* __restrict__ dst) {
  __shared__ float tile[32][33];
  const int tx = threadIdx.x, ty = threadIdx.y;
  const int bx = blockIdx.x * 32, by = blockIdx.y * 32;
#pragma unroll
  for (int i = 0; i < 32; i += 8)
    tile[ty + i][tx] = src[(size_t)(by + ty + i) * 1024 + bx + tx];
  __syncthreads();
#pragma unroll
  for (int i = 0; i < 32; i += 8)
    dst[(size_t)(bx + ty + i) * 1024 + by + tx] = f2bf(tile[tx][ty + i]);
}

// ---------------- GEMM: C[M,1024] = A[M,1024] @ B[1024,1024], BT[n][k] given ----------------
// MODE 0: bf16 out in [B,H,N,Dh] head-split layout.
// MODE 1: fp32 out row-major + bias.
// MODE 2: bf16 out transposed per head: [B,H,Dh,N] (for V), 4-row packed stores.
template <int MODE>
__global__ __launch_bounds__(256, 2) void gemm_bf16(const uint16_t* __restrict__ A,
                                                    const uint16_t* __restrict__ BT,
                                                    void* __restrict__ Cout,
                                                    const float* __restrict__ bias) {
  __shared__ __align__(16) uint16_t As[128 * 32];
  __shared__ __align__(16) uint16_t Bs[128 * 32];
  const int tid = threadIdx.x;
  const int wave = tid >> 6, lane = tid & 63;
  const int g = lane >> 4, c16 = lane & 15;
  const int m0 = blockIdx.y * 128, n0 = blockIdx.x * 128;
  const int wr = wave >> 1, wc = wave & 1;

  const f32x4 fzero = {0.f, 0.f, 0.f, 0.f};
  f32x4 acc[4][4];
#pragma unroll
  for (int i = 0; i < 4; ++i)
#pragma unroll
    for (int j = 0; j < 4; ++j) acc[i][j] = fzero;

  const int srow = wave * 32 + (lane >> 2);
  const int scol = (lane & 3) * 8;
  const uint16_t* ag0 = A + (size_t)(m0 + srow) * K_DIM + scol;
  const uint16_t* ag1 = A + (size_t)(m0 + srow + 16) * K_DIM + scol;
  const uint16_t* bg0 = BT + (size_t)(n0 + srow) * K_DIM + scol;
  const uint16_t* bg1 = BT + (size_t)(n0 + srow + 16) * K_DIM + scol;
  uint16_t* la0 = &As[(wave * 32) * 32];
  uint16_t* la1 = &As[(wave * 32 + 16) * 32];
  uint16_t* lb0 = &Bs[(wave * 32) * 32];
  uint16_t* lb1 = &Bs[(wave * 32 + 16) * 32];

  for (int kt = 0; kt < K_DIM / 32; ++kt) {
    __syncthreads();
    gld_lds16(ag0 + kt * 32, la0);
    gld_lds16(ag1 + kt * 32, la1);
    gld_lds16(bg0 + kt * 32, lb0);
    gld_lds16(bg1 + kt * 32, lb1);
    __syncthreads();
    bf16x8 avec[4], bvec[4];
#pragma unroll
    for (int i = 0; i < 4; ++i)
      avec[i] = *(const bf16x8*)&As[(wr * 64 + i * 16 + c16) * 32 + g * 8];
#pragma unroll
    for (int j = 0; j < 4; ++j)
      bvec[j] = *(const bf16x8*)&Bs[(wc * 64 + j * 16 + c16) * 32 + g * 8];
#pragma unroll
    for (int i = 0; i < 4; ++i)
#pragma unroll
      for (int j = 0; j < 4; ++j)
        acc[i][j] = __builtin_amdgcn_mfma_f32_16x16x32_bf16(avec[i], bvec[j], acc[i][j], 0, 0, 0);
  }

#pragma unroll
  for (int i = 0; i < 4; ++i) {
#pragma unroll
    for (int j = 0; j < 4; ++j) {
      const int col = n0 + wc * 64 + j * 16 + c16;
      if (MODE == 2) {
        // V^T layout [b*16+h][d][n]; rows g*4+r are 4 consecutive n -> pack 8B store
        const int h = col >> 6, d = col & 63;
        const int row0 = m0 + wr * 64 + i * 16 + g * 4;
        const int b = row0 >> 11, n = row0 & 2047;
        ushort4 o;
        o.x = f2bf(acc[i][j][0]); o.y = f2bf(acc[i][j][1]);
        o.z = f2bf(acc[i][j][2]); o.w = f2bf(acc[i][j][3]);
        *(ushort4*)&((uint16_t*)Cout)[(((size_t)(b * HEADS + h)) * DH + d) * N_SEQ + n] = o;
      } else {
#pragma unroll
        for (int r = 0; r < 4; ++r) {
          const int row = m0 + wr * 64 + i * 16 + g * 4 + r;
          if (MODE == 0) {
            const int b = row >> 11, n = row & 2047;
            const int h = col >> 6, d = col & 63;
            ((uint16_t*)Cout)[(((size_t)(b * HEADS + h)) * N_SEQ + n) * DH + d] = f2bf(acc[i][j][r]);
          } else {
            ((float*)Cout)[(size_t)row * 1024 + col] = acc[i][j][r] + bias[col];
          }
        }
      }
    }
  }
}

// ---------------- flash attention v2 ----------------
// 256 q-rows/block (64/wave as 4 x 16-col blocks), 64-key tiles.
// S^T = K·Q^T via MFMA (keys->rows), unnormalized softmax (no max/alpha/shuffles),
// P packed b64 into LDS in A-layout, V pre-transposed in global ([bh][d][n]).
__global__ __launch_bounds__(256, 2) void attention_k(const uint16_t* __restrict__ qm,
                                                      const uint16_t* __restrict__ km,
                                                      const uint16_t* __restrict__ vtm,
                                                      uint16_t* __restrict__ om) {
  __shared__ __align__(16) uint16_t Ks[64 * 72];
  __shared__ __align__(16) uint16_t Vs[64 * 72];
  __shared__ __align__(16) uint16_t Pt[4][64 * 88];  // stride 88: 16B-aligned rows, ~2-way banks
  const int tid = threadIdx.x;
  const int wave = tid >> 6, lane = tid & 63;
  const int g = lane >> 4, c16 = lane & 15;
  const int bh = blockIdx.y, b = bh >> 4, h = bh & 15;
  const int q0 = blockIdx.x * 256 + wave * 64;

  const uint16_t* qbase = qm + (size_t)bh * N_SEQ * DH;
  const uint16_t* kbase = km + (size_t)bh * N_SEQ * DH;
  const uint16_t* vbase = vtm + (size_t)bh * DH * N_SEQ;

  // Q as MFMA B-fragments (col = qrow = c16, k = d), straight from global
  bf16x8 qf[4][2];
#pragma unroll
  for (int qc = 0; qc < 4; ++qc) {
    const uint16_t* qp = qbase + (size_t)(q0 + qc * 16 + c16) * DH + g * 8;
    qf[qc][0] = *(const bf16x8*)qp;
    qf[qc][1] = *(const bf16x8*)(qp + 32);
  }

  const f32x4 fz = {0.f, 0.f, 0.f, 0.f};
  f32x4 oacc[4][4];
#pragma unroll
  for (int qc = 0; qc < 4; ++qc)
#pragma unroll
    for (int jt = 0; jt < 4; ++jt) oacc[qc][jt] = fz;
  float l[4] = {0.f, 0.f, 0.f, 0.f};

  const float CE = 0.1803368801f;  // 0.125 * log2(e)
  uint16_t* ptw = Pt[wave];

  for (int t = 0; t < N_SEQ / 64; ++t) {
    __syncthreads();
#pragma unroll
    for (int p = 0; p < 2; ++p) {
      // K tile: [key][d], contiguous
      const int e = (p * 256 + tid) * 8;
      *(uint4*)&Ks[(e >> 6) * 72 + (e & 63)] = *(const uint4*)&kbase[(size_t)t * 4096 + e];
      // V^T tile: rows d, cols key (row stride N_SEQ in global)
      const int c = p * 256 + tid;
      const int vr = c >> 3, vc = (c & 7) * 8;
      *(uint4*)&Vs[vr * 72 + vc] = *(const uint4*)&vbase[(size_t)vr * N_SEQ + t * 64 + vc];
    }
    __syncthreads();

    // S^T = K·Q^T ; p = exp(s*scale) unnormalized; pack 4 keys -> b64 into Pt[qrow][key]
#pragma unroll
    for (int kt = 0; kt < 4; ++kt) {
      bf16x8 kf0 = *(const bf16x8*)&Ks[(kt * 16 + c16) * 72 + g * 8];
      bf16x8 kf1 = *(const bf16x8*)&Ks[(kt * 16 + c16) * 72 + 32 + g * 8];
#pragma unroll
      for (int qc = 0; qc < 4; ++qc) {
        f32x4 z = fz;
        z = __builtin_amdgcn_mfma_f32_16x16x32_bf16(kf0, qf[qc][0], z, 0, 0, 0);
        z = __builtin_amdgcn_mfma_f32_16x16x32_bf16(kf1, qf[qc][1], z, 0, 0, 0);
        const float p0 = __builtin_amdgcn_exp2f(z[0] * CE);
        const float p1 = __builtin_amdgcn_exp2f(z[1] * CE);
        const float p2 = __builtin_amdgcn_exp2f(z[2] * CE);
        const float p3 = __builtin_amdgcn_exp2f(z[3] * CE);
        l[qc] += (p0 + p1) + (p2 + p3);
        bf16x4 pk;
        pk[0] = (__bf16)p0; pk[1] = (__bf16)p1; pk[2] = (__bf16)p2; pk[3] = (__bf16)p3;
        *(bf16x4*)&ptw[(qc * 16 + c16) * 88 + kt * 16 + g * 4] = pk;
      }
    }

    // O += P·V  (same-wave LDS write->read, DS pipe in-order; no barrier)
#pragma unroll
    for (int kc = 0; kc < 2; ++kc) {
      bf16x8 pa[4];
#pragma unroll
      for (int qc = 0; qc < 4; ++qc)
        pa[qc] = *(const bf16x8*)&ptw[(qc * 16 + c16) * 88 + kc * 32 + g * 8];
#pragma unroll
      for (int jt = 0; jt < 4; ++jt) {
        bf16x8 vb = *(const bf16x8*)&Vs[(jt * 16 + c16) * 72 + kc * 32 + g * 8];
#pragma unroll
        for (int qc = 0; qc < 4; ++qc)
          oacc[qc][jt] = __builtin_amdgcn_mfma_f32_16x16x32_bf16(pa[qc], vb, oacc[qc][jt], 0, 0, 0);
      }
    }
  }

  // finish l: butterfly over g-groups (bits 4,5)
#pragma unroll
  for (int qc = 0; qc < 4; ++qc) {
    l[qc] += __shfl_xor(l[qc], 16);
    l[qc] += __shfl_xor(l[qc], 32);
  }

  // epilogue: normalize, write O to [b][n][h*64+d] bf16
#pragma unroll
  for (int qc = 0; qc < 4; ++qc) {
#pragma unroll
    for (int r = 0; r < 4; ++r) {
      const float lr = __shfl(l[qc], g * 4 + r, 16);  // l for qrow qc*16 + g*4 + r
      const float inv = 1.f / lr;
      const int row = q0 + qc * 16 + g * 4 + r;
      const size_t base = ((size_t)b * N_SEQ + row) * 1024 + h * 64;
#pragma unroll
      for (int jt = 0; jt < 4; ++jt)
        om[base + jt * 16 + c16] = f2bf(oacc[qc][jt][r] * inv);
    }
  }
}

// ---------------- LayerNorm + residual ----------------
__global__ __launch_bounds__(256) void ln_res_k(const float* __restrict__ proj,
                                                const float* __restrict__ query,
                                                const float* __restrict__ gamma,
                                                const float* __restrict__ beta,
                                                float* __restrict__ out) {
  const int row = blockIdx.x;
  const int tid = threadIdx.x;
  const size_t base = (size_t)row * 1024 + tid * 4;
  float4 v = *(const float4*)(proj + base);
  float s = v.x + v.y + v.z + v.w;
  float s2 = v.x * v.x + v.y * v.y + v.z * v.z + v.w * v.w;
#pragma unroll
  for (int off = 1; off < 64; off <<= 1) {
    s += __shfl_xor(s, off);
    s2 += __shfl_xor(s2, off);
  }
  __shared__ float red[8];
  const int wave = tid >> 6, lane = tid & 63;
  if (lane == 0) { red[wave] = s; red[4 + wave] = s2; }
  __syncthreads();
  s = red[0] + red[1] + red[2] + red[3];
  s2 = red[4] + red[5] + red[6] + red[7];
  const float mu = s * (1.f / 1024.f);
  const float var = fmaxf(s2 * (1.f / 1024.f) - mu * mu, 0.f);
  const float rstd = rsqrtf(var + 1e-5f);
  float4 gq = *(const float4*)(gamma + tid * 4);
  float4 bq = *(const float4*)(beta + tid * 4);
  float4 qq = *(const float4*)(query + base);
  float4 o;
  o.x = (v.x - mu) * rstd * gq.x + bq.x + qq.x;
  o.y = (v.y - mu) * rstd * gq.y + bq.y + qq.y;
  o.z = (v.z - mu) * rstd * gq.z + bq.z + qq.z;
  o.w = (v.w - mu) * rstd * gq.w + bq.w + qq.w;
  *(float4*)(out + base) = o;
}

extern "C" void kernel_launch(void* const* d_in, const int* in_sizes, int n_in,
                              void* d_out, int out_size, void* d_ws, size_t ws_size,
                              hipStream_t stream) {
  (void)in_sizes; (void)n_in; (void)out_size; (void)ws_size;
  const float* query = (const float*)d_in[0];
  const float* key_ = (const float*)d_in[1];
  const float* value = (const float*)d_in[2];
  const float* Wq = (const float*)d_in[3];
  const float* Wk = (const float*)d_in[4];
  const float* Wv = (const float*)d_in[5];
  const float* Wo = (const float*)d_in[6];
  const float* bo = (const float*)d_in[7];
  const float* gamma = (const float*)d_in[8];
  const float* beta = (const float*)d_in[9];
  float* out = (float*)d_out;

  const size_t NELEM = (size_t)M_TOT * 1024;  // 8388608
  uint16_t* wsp = (uint16_t*)d_ws;
  uint16_t* WqT = wsp;
  uint16_t* WkT = WqT + 1024 * 1024;
  uint16_t* WvT = WkT + 1024 * 1024;
  uint16_t* WoT = WvT + 1024 * 1024;
  uint16_t* xq = WoT + 1024 * 1024;
  uint16_t* xk = xq + NELEM;
  uint16_t* xv = xk + NELEM;
  uint16_t* qb = xv + NELEM;
  uint16_t* kb = qb + NELEM;
  uint16_t* vt = kb + NELEM;  // V^T [b,h,d,n]
  uint16_t* attnO = xq;       // alias: xq dead after GEMM-q
  float* proj = (float*)xk;   // alias: xk+xv dead after GEMM-k/v (exactly 32MB)

  const int n4 = (int)(NELEM / 4);
  conv_bf16_k<<<8192, 256, 0, stream>>>(query, xq, n4);
  conv_bf16_k<<<8192, 256, 0, stream>>>(key_, xk, n4);
  conv_bf16_k<<<8192, 256, 0, stream>>>(value, xv, n4);

  dim3 tb(32, 8);
  transpose_conv<<<dim3(32, 32), tb, 0, stream>>>(Wq, WqT);
  transpose_conv<<<dim3(32, 32), tb, 0, stream>>>(Wk, WkT);
  transpose_conv<<<dim3(32, 32), tb, 0, stream>>>(Wv, WvT);
  transpose_conv<<<dim3(32, 32), tb, 0, stream>>>(Wo, WoT);

  dim3 gg(8, 64);
  gemm_bf16<0><<<gg, 256, 0, stream>>>(xq, WqT, qb, nullptr);
  gemm_bf16<0><<<gg, 256, 0, stream>>>(xk, WkT, kb, nullptr);
  gemm_bf16<2><<<gg, 256, 0, stream>>>(xv, WvT, vt, nullptr);

  attention_k<<<dim3(N_SEQ / 256, 64), 256, 0, stream>>>(qb, kb, vt, attnO);

  gemm_bf16<1><<<gg, 256, 0, stream>>>(attnO, WoT, proj, bo);

  ln_res_k<<<8192, 256, 0, stream>>>(proj, query, gamma, beta, out);
}

// Round 3
// 374.184 us; speedup vs baseline: 1.4439x; 1.0456x over previous
//
#include <hip/hip_runtime.h>
#include <stdint.h>

#define K_DIM 1024
#define B_SZ 4
#define N_SEQ 2048
#define HEADS 16
#define DH 64
#define M_TOT (B_SZ * N_SEQ)  // 8192

typedef __bf16 bf16x8 __attribute__((ext_vector_type(8)));
typedef __bf16 bf16x4 __attribute__((ext_vector_type(4)));
typedef float f32x4 __attribute__((ext_vector_type(4)));

typedef const uint32_t __attribute__((address_space(1))) gas_u32;
typedef uint32_t __attribute__((address_space(3))) las_u32;

#define CE_SCALE 0.1803368801f  // 0.125 * log2(e), folded into Q projection

__device__ __forceinline__ uint16_t f2bf(float f) {
  uint32_t u = __float_as_uint(f);
  u += 0x7FFFu + ((u >> 16) & 1u);  // round-nearest-even
  return (uint16_t)(u >> 16);
}

// async global->LDS, 16B per lane; LDS dest = base + lane*16 (wave-uniform base)
__device__ __forceinline__ void gld_lds16(const uint16_t* g, uint16_t* lds) {
  __builtin_amdgcn_global_load_lds((gas_u32*)g, (las_u32*)lds, 16, 0, 0);
}

// ---------------- fp32 -> bf16 convert (batched over 3 tensors via blockIdx.y) ----
__global__ __launch_bounds__(256) void conv_bf16_k(const float* __restrict__ s0,
                                                   const float* __restrict__ s1,
                                                   const float* __restrict__ s2,
                                                   uint16_t* __restrict__ dstbase, int n4) {
  const int z = blockIdx.y;
  const float* src = (z == 0) ? s0 : (z == 1) ? s1 : s2;
  uint16_t* dst = dstbase + (size_t)z * M_TOT * K_DIM;
  int i = blockIdx.x * blockDim.x + threadIdx.x;
  if (i < n4) {
    float4 v = ((const float4*)src)[i];
    ushort4 o;
    o.x = f2bf(v.x); o.y = f2bf(v.y); o.z = f2bf(v.z); o.w = f2bf(v.w);
    ((ushort4*)dst)[i] = o;
  }
}

// ------------- transpose + convert weights (batched over 4 via blockIdx.z) -------
__global__ __launch_bounds__(256) void transpose_conv(const float* __restrict__ s0,
                                                      const float* __restrict__ s1,
                                                      const float* __restrict__ s2,
                                                      const float* __restrict__ s3,
                                                      uint16_t* __restrict__ dstbase) {
  __shared__ float tile[32][33];
  const int z = blockIdx.z;
  const float* src = (z == 0) ? s0 : (z == 1) ? s1 : (z == 2) ? s2 : s3;
  uint16_t* dst = dstbase + (size_t)z * 1024 * 1024;
  const int tx = threadIdx.x, ty = threadIdx.y;
  const int bx = blockIdx.x * 32, by = blockIdx.y * 32;
#pragma unroll
  for (int i = 0; i < 32; i += 8)
    tile[ty + i][tx] = src[(size_t)(by + ty + i) * 1024 + bx + tx];
  __syncthreads();
#pragma unroll
  for (int i = 0; i < 32; i += 8)
    dst[(size_t)(bx + ty + i) * 1024 + by + tx] = f2bf(tile[tx][ty + i]);
}

// ---------------- GEMM: C[M,1024] = A[M,1024] @ B[1024,1024], BT[n][k] given -----
// MODE 0: bf16 out [B,H,N,Dh]; blockIdx.z batches Q (z=0, scaled by CE) and K (z=1).
// MODE 1: fp32 out row-major + bias.
// MODE 2: bf16 out transposed per head [B,H,Dh,N] (for V), 4-row packed stores.
template <int MODE>
__global__ __launch_bounds__(256, 2) void gemm_bf16(const uint16_t* __restrict__ A,
                                                    const uint16_t* __restrict__ BT,
                                                    void* __restrict__ Cout,
                                                    const float* __restrict__ bias) {
  __shared__ __align__(16) uint16_t As[128 * 32];
  __shared__ __align__(16) uint16_t Bs[128 * 32];
  const int tid = threadIdx.x;
  const int wave = tid >> 6, lane = tid & 63;
  const int g = lane >> 4, c16 = lane & 15;
  const int m0 = blockIdx.y * 128, n0 = blockIdx.x * 128;
  const int wr = wave >> 1, wc = wave & 1;
  float scale = 1.f;
  if (MODE == 0) {
    const int z = blockIdx.z;
    A += (size_t)z * M_TOT * K_DIM;
    BT += (size_t)z * 1024 * 1024;
    Cout = (void*)((uint16_t*)Cout + (size_t)z * M_TOT * K_DIM);
    scale = (z == 0) ? CE_SCALE : 1.f;
  }

  const f32x4 fzero = {0.f, 0.f, 0.f, 0.f};
  f32x4 acc[4][4];
#pragma unroll
  for (int i = 0; i < 4; ++i)
#pragma unroll
    for (int j = 0; j < 4; ++j) acc[i][j] = fzero;

  const int srow = wave * 32 + (lane >> 2);
  const int scol = (lane & 3) * 8;
  const uint16_t* ag0 = A + (size_t)(m0 + srow) * K_DIM + scol;
  const uint16_t* ag1 = A + (size_t)(m0 + srow + 16) * K_DIM + scol;
  const uint16_t* bg0 = BT + (size_t)(n0 + srow) * K_DIM + scol;
  const uint16_t* bg1 = BT + (size_t)(n0 + srow + 16) * K_DIM + scol;
  uint16_t* la0 = &As[(wave * 32) * 32];
  uint16_t* la1 = &As[(wave * 32 + 16) * 32];
  uint16_t* lb0 = &Bs[(wave * 32) * 32];
  uint16_t* lb1 = &Bs[(wave * 32 + 16) * 32];

  for (int kt = 0; kt < K_DIM / 32; ++kt) {
    __syncthreads();
    gld_lds16(ag0 + kt * 32, la0);
    gld_lds16(ag1 + kt * 32, la1);
    gld_lds16(bg0 + kt * 32, lb0);
    gld_lds16(bg1 + kt * 32, lb1);
    __syncthreads();
    bf16x8 avec[4], bvec[4];
#pragma unroll
    for (int i = 0; i < 4; ++i)
      avec[i] = *(const bf16x8*)&As[(wr * 64 + i * 16 + c16) * 32 + g * 8];
#pragma unroll
    for (int j = 0; j < 4; ++j)
      bvec[j] = *(const bf16x8*)&Bs[(wc * 64 + j * 16 + c16) * 32 + g * 8];
#pragma unroll
    for (int i = 0; i < 4; ++i)
#pragma unroll
      for (int j = 0; j < 4; ++j)
        acc[i][j] = __builtin_amdgcn_mfma_f32_16x16x32_bf16(avec[i], bvec[j], acc[i][j], 0, 0, 0);
  }

#pragma unroll
  for (int i = 0; i < 4; ++i) {
#pragma unroll
    for (int j = 0; j < 4; ++j) {
      const int col = n0 + wc * 64 + j * 16 + c16;
      if (MODE == 2) {
        const int h = col >> 6, d = col & 63;
        const int row0 = m0 + wr * 64 + i * 16 + g * 4;
        const int b = row0 >> 11, n = row0 & 2047;
        ushort4 o;
        o.x = f2bf(acc[i][j][0]); o.y = f2bf(acc[i][j][1]);
        o.z = f2bf(acc[i][j][2]); o.w = f2bf(acc[i][j][3]);
        *(ushort4*)&((uint16_t*)Cout)[(((size_t)(b * HEADS + h)) * DH + d) * N_SEQ + n] = o;
      } else {
#pragma unroll
        for (int r = 0; r < 4; ++r) {
          const int row = m0 + wr * 64 + i * 16 + g * 4 + r;
          if (MODE == 0) {
            const int b = row >> 11, n = row & 2047;
            const int h = col >> 6, d = col & 63;
            ((uint16_t*)Cout)[(((size_t)(b * HEADS + h)) * N_SEQ + n) * DH + d] =
                f2bf(acc[i][j][r] * scale);
          } else {
            ((float*)Cout)[(size_t)row * 1024 + col] = acc[i][j][r] + bias[col];
          }
        }
      }
    }
  }
}

// ---------------- flash attention v3 ----------------
// 128 q-rows/block (32/wave as 2 x 16-col blocks), 64-key tiles, grid 1024 blocks.
// XOR-swizzled LDS (chunk8 ^= row&7) -> all DS ops <=2-way (free).
// S^T = K·Q^T, unnormalized softmax (scale pre-folded into Q), P b64-packed in
// A-layout, V pre-transposed in global ([bh][d][n]).
__global__ __launch_bounds__(256, 4) void attention_k(const uint16_t* __restrict__ qm,
                                                      const uint16_t* __restrict__ km,
                                                      const uint16_t* __restrict__ vtm,
                                                      uint16_t* __restrict__ om) {
  __shared__ __align__(16) uint16_t Ks[64 * 64];
  __shared__ __align__(16) uint16_t Vs[64 * 64];
  __shared__ __align__(16) uint16_t Pt[4][32 * 64];
  const int tid = threadIdx.x;
  const int wave = tid >> 6, lane = tid & 63;
  const int g = lane >> 4, c16 = lane & 15;
  const int bh = blockIdx.y, b = bh >> 4, h = bh & 15;
  const int q0 = blockIdx.x * 128 + wave * 32;

  const uint16_t* qbase = qm + (size_t)bh * N_SEQ * DH;
  const uint16_t* kbase = km + (size_t)bh * N_SEQ * DH;
  const uint16_t* vbase = vtm + (size_t)bh * DH * N_SEQ;

  // Q as MFMA B-fragments (col = qrow = c16, k = d), straight from global
  bf16x8 qf[2][2];
#pragma unroll
  for (int qc = 0; qc < 2; ++qc) {
    const uint16_t* qp = qbase + (size_t)(q0 + qc * 16 + c16) * DH + g * 8;
    qf[qc][0] = *(const bf16x8*)qp;
    qf[qc][1] = *(const bf16x8*)(qp + 32);
  }

  const f32x4 fz = {0.f, 0.f, 0.f, 0.f};
  f32x4 oacc[2][4];
#pragma unroll
  for (int qc = 0; qc < 2; ++qc)
#pragma unroll
    for (int jt = 0; jt < 4; ++jt) oacc[qc][jt] = fz;
  float l[2] = {0.f, 0.f};

  uint16_t* ptw = Pt[wave];
  const int sw = c16 & 7;  // XOR swizzle key for fragment reads (row&7 == c16&7)

  for (int t = 0; t < N_SEQ / 64; ++t) {
    __syncthreads();
#pragma unroll
    for (int p = 0; p < 2; ++p) {
      const int idx = p * 256 + tid;
      // K tile [key][d], contiguous in global; swizzle chunk8 by row&7
      {
        const int e = idx * 8, row = e >> 6, ch = idx & 7;
        *(uint4*)&Ks[row * 64 + ((ch ^ (row & 7)) << 3)] =
            *(const uint4*)&kbase[(size_t)t * 4096 + e];
      }
      // V^T tile: rows d (stride N_SEQ in global), cols key
      {
        const int vr = idx >> 3, ch = idx & 7;
        *(uint4*)&Vs[vr * 64 + ((ch ^ (vr & 7)) << 3)] =
            *(const uint4*)&vbase[(size_t)vr * N_SEQ + t * 64 + ch * 8];
      }
    }
    __syncthreads();

    // S^T = K·Q^T ; p = exp2(s) (scale pre-folded into Q); pack b64 -> Pt A-layout
#pragma unroll
    for (int kt = 0; kt < 4; ++kt) {
      const int krow = kt * 16 + c16;
      bf16x8 kf0 = *(const bf16x8*)&Ks[krow * 64 + ((g ^ sw) << 3)];
      bf16x8 kf1 = *(const bf16x8*)&Ks[krow * 64 + (((4 + g) ^ sw) << 3)];
#pragma unroll
      for (int qc = 0; qc < 2; ++qc) {
        f32x4 z = fz;
        z = __builtin_amdgcn_mfma_f32_16x16x32_bf16(kf0, qf[qc][0], z, 0, 0, 0);
        z = __builtin_amdgcn_mfma_f32_16x16x32_bf16(kf1, qf[qc][1], z, 0, 0, 0);
        const float p0 = __builtin_amdgcn_exp2f(z[0]);
        const float p1 = __builtin_amdgcn_exp2f(z[1]);
        const float p2 = __builtin_amdgcn_exp2f(z[2]);
        const float p3 = __builtin_amdgcn_exp2f(z[3]);
        l[qc] += (p0 + p1) + (p2 + p3);
        bf16x4 pk;
        pk[0] = (__bf16)p0; pk[1] = (__bf16)p1; pk[2] = (__bf16)p2; pk[3] = (__bf16)p3;
        // row = qc*16+c16, col = kt*16+g*4 -> chunk8 = kt*2+(g>>1), sub = (g&1)*4
        *(bf16x4*)&ptw[(qc * 16 + c16) * 64 + (((kt * 2 + (g >> 1)) ^ sw) << 3) + (g & 1) * 4] = pk;
      }
    }

    // O += P·V  (same-wave LDS write->read; DS pipe in-order, no barrier)
#pragma unroll
    for (int kc = 0; kc < 2; ++kc) {
      bf16x8 pa[2];
#pragma unroll
      for (int qc = 0; qc < 2; ++qc)
        pa[qc] = *(const bf16x8*)&ptw[(qc * 16 + c16) * 64 + (((kc * 4 + g) ^ sw) << 3)];
#pragma unroll
      for (int jt = 0; jt < 4; ++jt) {
        const int vrow = jt * 16 + c16;
        bf16x8 vb = *(const bf16x8*)&Vs[vrow * 64 + (((kc * 4 + g) ^ sw) << 3)];
#pragma unroll
        for (int qc = 0; qc < 2; ++qc)
          oacc[qc][jt] = __builtin_amdgcn_mfma_f32_16x16x32_bf16(pa[qc], vb, oacc[qc][jt], 0, 0, 0);
      }
    }
  }

  // finish l: reduce over g-quads (lane bits 4,5)
#pragma unroll
  for (int qc = 0; qc < 2; ++qc) {
    l[qc] += __shfl_xor(l[qc], 16);
    l[qc] += __shfl_xor(l[qc], 32);
  }

  // epilogue: normalize, write O to [b][n][h*64+d] bf16
#pragma unroll
  for (int qc = 0; qc < 2; ++qc) {
#pragma unroll
    for (int r = 0; r < 4; ++r) {
      const float lr = __shfl(l[qc], g * 4 + r, 16);  // l for qrow qc*16 + g*4 + r
      const float inv = 1.f / lr;
      const int row = q0 + qc * 16 + g * 4 + r;
      const size_t base = ((size_t)b * N_SEQ + row) * 1024 + h * 64;
#pragma unroll
      for (int jt = 0; jt < 4; ++jt)
        om[base + jt * 16 + c16] = f2bf(oacc[qc][jt][r] * inv);
    }
  }
}

// ---------------- LayerNorm + residual ----------------
__global__ __launch_bounds__(256) void ln_res_k(const float* __restrict__ proj,
                                                const float* __restrict__ query,
                                                const float* __restrict__ gamma,
                                                const float* __restrict__ beta,
                                                float* __restrict__ out) {
  const int row = blockIdx.x;
  const int tid = threadIdx.x;
  const size_t base = (size_t)row * 1024 + tid * 4;
  float4 v = *(const float4*)(proj + base);
  float s = v.x + v.y + v.z + v.w;
  float s2 = v.x * v.x + v.y * v.y + v.z * v.z + v.w * v.w;
#pragma unroll
  for (int off = 1; off < 64; off <<= 1) {
    s += __shfl_xor(s, off);
    s2 += __shfl_xor(s2, off);
  }
  __shared__ float red[8];
  const int wave = tid >> 6, lane = tid & 63;
  if (lane == 0) { red[wave] = s; red[4 + wave] = s2; }
  __syncthreads();
  s = red[0] + red[1] + red[2] + red[3];
  s2 = red[4] + red[5] + red[6] + red[7];
  const float mu = s * (1.f / 1024.f);
  const float var = fmaxf(s2 * (1.f / 1024.f) - mu * mu, 0.f);
  const float rstd = rsqrtf(var + 1e-5f);
  float4 gq = *(const float4*)(gamma + tid * 4);
  float4 bq = *(const float4*)(beta + tid * 4);
  float4 qq = *(const float4*)(query + base);
  float4 o;
  o.x = (v.x - mu) * rstd * gq.x + bq.x + qq.x;
  o.y = (v.y - mu) * rstd * gq.y + bq.y + qq.y;
  o.z = (v.z - mu) * rstd * gq.z + bq.z + qq.z;
  o.w = (v.w - mu) * rstd * gq.w + bq.w + qq.w;
  *(float4*)(out + base) = o;
}

extern "C" void kernel_launch(void* const* d_in, const int* in_sizes, int n_in,
                              void* d_out, int out_size, void* d_ws, size_t ws_size,
                              hipStream_t stream) {
  (void)in_sizes; (void)n_in; (void)out_size; (void)ws_size;
  const float* query = (const float*)d_in[0];
  const float* key_ = (const float*)d_in[1];
  const float* value = (const float*)d_in[2];
  const float* Wq = (const float*)d_in[3];
  const float* Wk = (const float*)d_in[4];
  const float* Wv = (const float*)d_in[5];
  const float* Wo = (const float*)d_in[6];
  const float* bo = (const float*)d_in[7];
  const float* gamma = (const float*)d_in[8];
  const float* beta = (const float*)d_in[9];
  float* out = (float*)d_out;

  const size_t NELEM = (size_t)M_TOT * 1024;  // 8388608
  uint16_t* wsp = (uint16_t*)d_ws;
  uint16_t* WqT = wsp;                 // 4 x 1M bf16 (contiguous: Wq,Wk,Wv,Wo)
  uint16_t* WvT = WqT + 2 * 1024 * 1024;
  uint16_t* WoT = WqT + 3 * 1024 * 1024;
  uint16_t* xq = WqT + 4 * 1024 * 1024;  // 3 x NELEM (contiguous: xq,xk,xv)
  uint16_t* xv = xq + 2 * NELEM;
  uint16_t* qb = xq + 3 * NELEM;  // 2 x NELEM (qb,kb contiguous)
  uint16_t* vt = qb + 2 * NELEM;  // V^T [b,h,d,n]
  uint16_t* attnO = xq;           // alias: xq dead after QK-GEMM
  float* proj = (float*)(xq + NELEM);  // alias: xk+xv dead after GEMMs (32MB)

  const int n4 = (int)(NELEM / 4);
  conv_bf16_k<<<dim3(8192, 3), 256, 0, stream>>>(query, key_, value, xq, n4);

  transpose_conv<<<dim3(32, 32, 4), dim3(32, 8), 0, stream>>>(Wq, Wk, Wv, Wo, WqT);

  gemm_bf16<0><<<dim3(8, 64, 2), 256, 0, stream>>>(xq, WqT, qb, nullptr);
  gemm_bf16<2><<<dim3(8, 64), 256, 0, stream>>>(xv, WvT, vt, nullptr);

  attention_k<<<dim3(N_SEQ / 128, 64), 256, 0, stream>>>(qb, qb + NELEM, vt, attnO);

  gemm_bf16<1><<<dim3(8, 64), 256, 0, stream>>>(attnO, WoT, proj, bo);

  ln_res_k<<<8192, 256, 0, stream>>>(proj, query, gamma, beta, out);
}

// Round 4
// 365.040 us; speedup vs baseline: 1.4801x; 1.0250x over previous
//
#include <hip/hip_runtime.h>
#include <stdint.h>

#define K_DIM 1024
#define B_SZ 4
#define N_SEQ 2048
#define HEADS 16
#define DH 64
#define M_TOT (B_SZ * N_SEQ)  // 8192

typedef __bf16 bf16x8 __attribute__((ext_vector_type(8)));
typedef __bf16 bf16x4 __attribute__((ext_vector_type(4)));
typedef float f32x4 __attribute__((ext_vector_type(4)));

typedef const uint32_t __attribute__((address_space(1))) gas_u32;
typedef uint32_t __attribute__((address_space(3))) las_u32;

#define CE_SCALE 0.1803368801f  // 0.125 * log2(e), folded into Q projection

__device__ __forceinline__ uint16_t f2bf(float f) {
  uint32_t u = __float_as_uint(f);
  u += 0x7FFFu + ((u >> 16) & 1u);  // round-nearest-even
  return (uint16_t)(u >> 16);
}

__device__ __forceinline__ void gld_lds16(const uint16_t* g, uint16_t* lds) {
  __builtin_amdgcn_global_load_lds((gas_u32*)g, (las_u32*)lds, 16, 0, 0);
}

// ---------------- fp32 -> bf16 convert (batched over 3 tensors) ----------------
__global__ __launch_bounds__(256) void conv_bf16_k(const float* __restrict__ s0,
                                                   const float* __restrict__ s1,
                                                   const float* __restrict__ s2,
                                                   uint16_t* __restrict__ dstbase, int n4) {
  const int z = blockIdx.y;
  const float* src = (z == 0) ? s0 : (z == 1) ? s1 : s2;
  uint16_t* dst = dstbase + (size_t)z * M_TOT * K_DIM;
  int i = blockIdx.x * blockDim.x + threadIdx.x;
  if (i < n4) {
    float4 v = ((const float4*)src)[i];
    ushort4 o;
    o.x = f2bf(v.x); o.y = f2bf(v.y); o.z = f2bf(v.z); o.w = f2bf(v.w);
    ((ushort4*)dst)[i] = o;
  }
}

// ------------- transpose + convert weights (batched over 4) ----------------------
__global__ __launch_bounds__(256) void transpose_conv(const float* __restrict__ s0,
                                                      const float* __restrict__ s1,
                                                      const float* __restrict__ s2,
                                                      const float* __restrict__ s3,
                                                      uint16_t* __restrict__ dstbase) {
  __shared__ float tile[32][33];
  const int z = blockIdx.z;
  const float* src = (z == 0) ? s0 : (z == 1) ? s1 : (z == 2) ? s2 : s3;
  uint16_t* dst = dstbase + (size_t)z * 1024 * 1024;
  const int tx = threadIdx.x, ty = threadIdx.y;
  const int bx = blockIdx.x * 32, by = blockIdx.y * 32;
#pragma unroll
  for (int i = 0; i < 32; i += 8)
    tile[ty + i][tx] = src[(size_t)(by + ty + i) * 1024 + bx + tx];
  __syncthreads();
#pragma unroll
  for (int i = 0; i < 32; i += 8)
    dst[(size_t)(bx + ty + i) * 1024 + by + tx] = f2bf(tile[tx][ty + i]);
}

// ---------------- GEMM: C[M,1024] = A[M,1024] @ B[1024,1024], BT[n][k] given -----
// MODE 3: fused QKV (z=0 Q scaled -> [B,H,N,Dh]; z=1 K -> [B,H,N,Dh]; z=2 V -> [B,H,Dh,N])
// MODE 1: fp32 out row-major + bias (output projection).
template <int MODE>
__global__ __launch_bounds__(256, 2) void gemm_bf16(const uint16_t* __restrict__ A,
                                                    const uint16_t* __restrict__ BT,
                                                    void* __restrict__ Cout,
                                                    const float* __restrict__ bias) {
  __shared__ __align__(16) uint16_t As[128 * 32];
  __shared__ __align__(16) uint16_t Bs[128 * 32];
  const int tid = threadIdx.x;
  const int wave = tid >> 6, lane = tid & 63;
  const int g = lane >> 4, c16 = lane & 15;
  const int m0 = blockIdx.y * 128, n0 = blockIdx.x * 128;
  const int wr = wave >> 1, wc = wave & 1;
  int z = 0;
  float scale = 1.f;
  if (MODE == 3) {
    z = blockIdx.z;
    A += (size_t)z * M_TOT * K_DIM;
    BT += (size_t)z * 1024 * 1024;
    scale = (z == 0) ? CE_SCALE : 1.f;
  }

  const f32x4 fzero = {0.f, 0.f, 0.f, 0.f};
  f32x4 acc[4][4];
#pragma unroll
  for (int i = 0; i < 4; ++i)
#pragma unroll
    for (int j = 0; j < 4; ++j) acc[i][j] = fzero;

  const int srow = wave * 32 + (lane >> 2);
  const int scol = (lane & 3) * 8;
  const uint16_t* ag0 = A + (size_t)(m0 + srow) * K_DIM + scol;
  const uint16_t* ag1 = A + (size_t)(m0 + srow + 16) * K_DIM + scol;
  const uint16_t* bg0 = BT + (size_t)(n0 + srow) * K_DIM + scol;
  const uint16_t* bg1 = BT + (size_t)(n0 + srow + 16) * K_DIM + scol;
  uint16_t* la0 = &As[(wave * 32) * 32];
  uint16_t* la1 = &As[(wave * 32 + 16) * 32];
  uint16_t* lb0 = &Bs[(wave * 32) * 32];
  uint16_t* lb1 = &Bs[(wave * 32 + 16) * 32];

  for (int kt = 0; kt < K_DIM / 32; ++kt) {
    __syncthreads();
    gld_lds16(ag0 + kt * 32, la0);
    gld_lds16(ag1 + kt * 32, la1);
    gld_lds16(bg0 + kt * 32, lb0);
    gld_lds16(bg1 + kt * 32, lb1);
    __syncthreads();
    bf16x8 avec[4], bvec[4];
#pragma unroll
    for (int i = 0; i < 4; ++i)
      avec[i] = *(const bf16x8*)&As[(wr * 64 + i * 16 + c16) * 32 + g * 8];
#pragma unroll
    for (int j = 0; j < 4; ++j)
      bvec[j] = *(const bf16x8*)&Bs[(wc * 64 + j * 16 + c16) * 32 + g * 8];
#pragma unroll
    for (int i = 0; i < 4; ++i)
#pragma unroll
      for (int j = 0; j < 4; ++j)
        acc[i][j] = __builtin_amdgcn_mfma_f32_16x16x32_bf16(avec[i], bvec[j], acc[i][j], 0, 0, 0);
  }

#pragma unroll
  for (int i = 0; i < 4; ++i) {
#pragma unroll
    for (int j = 0; j < 4; ++j) {
      const int col = n0 + wc * 64 + j * 16 + c16;
      if (MODE == 3 && z == 2) {
        const int h = col >> 6, d = col & 63;
        const int row0 = m0 + wr * 64 + i * 16 + g * 4;
        const int b = row0 >> 11, n = row0 & 2047;
        ushort4 o;
        o.x = f2bf(acc[i][j][0]); o.y = f2bf(acc[i][j][1]);
        o.z = f2bf(acc[i][j][2]); o.w = f2bf(acc[i][j][3]);
        *(ushort4*)&((uint16_t*)Cout)[(size_t)2 * M_TOT * 1024 +
                                      (((size_t)(b * HEADS + h)) * DH + d) * N_SEQ + n] = o;
      } else {
#pragma unroll
        for (int r = 0; r < 4; ++r) {
          const int row = m0 + wr * 64 + i * 16 + g * 4 + r;
          if (MODE == 3) {
            const int b = row >> 11, n = row & 2047;
            const int h = col >> 6, d = col & 63;
            ((uint16_t*)Cout)[(size_t)z * M_TOT * 1024 +
                              (((size_t)(b * HEADS + h)) * N_SEQ + n) * DH + d] =
                f2bf(acc[i][j][r] * scale);
          } else {
            ((float*)Cout)[(size_t)row * 1024 + col] = acc[i][j][r] + bias[col];
          }
        }
      }
    }
  }
}

// ---------------- flash attention v4 ----------------
// 256 q/block (64/wave, qc=4), 64-key tiles, grid 512, XOR-swizzled LDS,
// VGPR-prefetch pipeline (loads for tile t+1 in flight across compute of t).
__global__ __launch_bounds__(256, 2) void attention_k(const uint16_t* __restrict__ qm,
                                                      const uint16_t* __restrict__ km,
                                                      const uint16_t* __restrict__ vtm,
                                                      uint16_t* __restrict__ om) {
  __shared__ __align__(16) uint16_t Ks[64 * 64];
  __shared__ __align__(16) uint16_t Vs[64 * 64];
  __shared__ __align__(16) uint16_t Pt[4][64 * 64];
  const int tid = threadIdx.x;
  const int wave = tid >> 6, lane = tid & 63;
  const int g = lane >> 4, c16 = lane & 15;
  const int bh = blockIdx.y, b = bh >> 4, h = bh & 15;
  const int q0 = blockIdx.x * 256 + wave * 64;

  const uint16_t* qbase = qm + (size_t)bh * N_SEQ * DH;
  const uint16_t* kbase = km + (size_t)bh * N_SEQ * DH;
  const uint16_t* vbase = vtm + (size_t)bh * DH * N_SEQ;

  bf16x8 qf[4][2];
#pragma unroll
  for (int qc = 0; qc < 4; ++qc) {
    const uint16_t* qp = qbase + (size_t)(q0 + qc * 16 + c16) * DH + g * 8;
    qf[qc][0] = *(const bf16x8*)qp;
    qf[qc][1] = *(const bf16x8*)(qp + 32);
  }

  const f32x4 fz = {0.f, 0.f, 0.f, 0.f};
  f32x4 oacc[4][4];
#pragma unroll
  for (int qc = 0; qc < 4; ++qc)
#pragma unroll
    for (int jt = 0; jt < 4; ++jt) oacc[qc][jt] = fz;
  float l[4] = {0.f, 0.f, 0.f, 0.f};

  uint16_t* ptw = Pt[wave];
  const int sw = c16 & 7;

  const int ch = tid & 7;
  const int krow0 = tid >> 3, krow1 = (256 + tid) >> 3;
  const int kdst0 = krow0 * 64 + ((ch ^ (krow0 & 7)) << 3);
  const int kdst1 = krow1 * 64 + ((ch ^ (krow1 & 7)) << 3);

  uint4 kp0, kp1, vp0, vp1;
  kp0 = *(const uint4*)&kbase[(size_t)tid * 8];
  kp1 = *(const uint4*)&kbase[(size_t)(256 + tid) * 8];
  vp0 = *(const uint4*)&vbase[(size_t)krow0 * N_SEQ + ch * 8];
  vp1 = *(const uint4*)&vbase[(size_t)krow1 * N_SEQ + ch * 8];
  *(uint4*)&Ks[kdst0] = kp0;
  *(uint4*)&Ks[kdst1] = kp1;
  *(uint4*)&Vs[kdst0] = vp0;
  *(uint4*)&Vs[kdst1] = vp1;
  __syncthreads();

  for (int t = 0; t < N_SEQ / 64; ++t) {
    if (t < N_SEQ / 64 - 1) {
      const size_t ko = (size_t)(t + 1) * 4096;
      const int vc = (t + 1) * 64;
      kp0 = *(const uint4*)&kbase[ko + (size_t)tid * 8];
      kp1 = *(const uint4*)&kbase[ko + (size_t)(256 + tid) * 8];
      vp0 = *(const uint4*)&vbase[(size_t)krow0 * N_SEQ + vc + ch * 8];
      vp1 = *(const uint4*)&vbase[(size_t)krow1 * N_SEQ + vc + ch * 8];
    }

#pragma unroll
    for (int kt = 0; kt < 4; ++kt) {
      const int krow = kt * 16 + c16;
      bf16x8 kf0 = *(const bf16x8*)&Ks[krow * 64 + ((g ^ sw) << 3)];
      bf16x8 kf1 = *(const bf16x8*)&Ks[krow * 64 + (((4 + g) ^ sw) << 3)];
      const int pcol = (((kt * 2 + (g >> 1)) ^ sw) << 3) + (g & 1) * 4;
#pragma unroll
      for (int qc = 0; qc < 4; ++qc) {
        f32x4 z = fz;
        z = __builtin_amdgcn_mfma_f32_16x16x32_bf16(kf0, qf[qc][0], z, 0, 0, 0);
        z = __builtin_amdgcn_mfma_f32_16x16x32_bf16(kf1, qf[qc][1], z, 0, 0, 0);
        const float p0 = __builtin_amdgcn_exp2f(z[0]);
        const float p1 = __builtin_amdgcn_exp2f(z[1]);
        const float p2 = __builtin_amdgcn_exp2f(z[2]);
        const float p3 = __builtin_amdgcn_exp2f(z[3]);
        l[qc] += (p0 + p1) + (p2 + p3);
        bf16x4 pk;
        pk[0] = (__bf16)p0; pk[1] = (__bf16)p1; pk[2] = (__bf16)p2; pk[3] = (__bf16)p3;
        *(bf16x4*)&ptw[(qc * 16 + c16) * 64 + pcol] = pk;
      }
    }

#pragma unroll
    for (int kc = 0; kc < 2; ++kc) {
      const int fcol = ((kc * 4 + g) ^ sw) << 3;
      bf16x8 pa[4];
#pragma unroll
      for (int qc = 0; qc < 4; ++qc)
        pa[qc] = *(const bf16x8*)&ptw[(qc * 16 + c16) * 64 + fcol];
#pragma unroll
      for (int jt = 0; jt < 4; ++jt) {
        bf16x8 vb = *(const bf16x8*)&Vs[(jt * 16 + c16) * 64 + fcol];
#pragma unroll
        for (int qc = 0; qc < 4; ++qc)
          oacc[qc][jt] = __builtin_amdgcn_mfma_f32_16x16x32_bf16(pa[qc], vb, oacc[qc][jt], 0, 0, 0);
      }
    }

    if (t < N_SEQ / 64 - 1) {
      __syncthreads();
      *(uint4*)&Ks[kdst0] = kp0;
      *(uint4*)&Ks[kdst1] = kp1;
      *(uint4*)&Vs[kdst0] = vp0;
      *(uint4*)&Vs[kdst1] = vp1;
      __syncthreads();
    }
  }

#pragma unroll
  for (int qc = 0; qc < 4; ++qc) {
    l[qc] += __shfl_xor(l[qc], 16);
    l[qc] += __shfl_xor(l[qc], 32);
  }

#pragma unroll
  for (int qc = 0; qc < 4; ++qc) {
#pragma unroll
    for (int r = 0; r < 4; ++r) {
      const float lr = __shfl(l[qc], g * 4 + r, 16);
      const float inv = 1.f / lr;
      const int row = q0 + qc * 16 + g * 4 + r;
      const size_t base = ((size_t)b * N_SEQ + row) * 1024 + h * 64;
#pragma unroll
      for (int jt = 0; jt < 4; ++jt)
        om[base + jt * 16 + c16] = f2bf(oacc[qc][jt][r] * inv);
    }
  }
}

// ---------------- LayerNorm + residual ----------------
__global__ __launch_bounds__(256) void ln_res_k(const float* __restrict__ proj,
                                                const float* __restrict__ query,
                                                const float* __restrict__ gamma,
                                                const float* __restrict__ beta,
                                                float* __restrict__ out) {
  const int row = blockIdx.x;
  const int tid = threadIdx.x;
  const size_t base = (size_t)row * 1024 + tid * 4;
  float4 v = *(const float4*)(proj + base);
  float s = v.x + v.y + v.z + v.w;
  float s2 = v.x * v.x + v.y * v.y + v.z * v.z + v.w * v.w;
#pragma unroll
  for (int off = 1; off < 64; off <<= 1) {
    s += __shfl_xor(s, off);
    s2 += __shfl_xor(s2, off);
  }
  __shared__ float red[8];
  const int wave = tid >> 6, lane = tid & 63;
  if (lane == 0) { red[wave] = s; red[4 + wave] = s2; }
  __syncthreads();
  s = red[0] + red[1] + red[2] + red[3];
  s2 = red[4] + red[5] + red[6] + red[7];
  const float mu = s * (1.f / 1024.f);
  const float var = fmaxf(s2 * (1.f / 1024.f) - mu * mu, 0.f);
  const float rstd = rsqrtf(var + 1e-5f);
  float4 gq = *(const float4*)(gamma + tid * 4);
  float4 bq = *(const float4*)(beta + tid * 4);
  float4 qq = *(const float4*)(query + base);
  float4 o;
  o.x = (v.x - mu) * rstd * gq.x + bq.x + qq.x;
  o.y = (v.y - mu) * rstd * gq.y + bq.y + qq.y;
  o.z = (v.z - mu) * rstd * gq.z + bq.z + qq.z;
  o.w = (v.w - mu) * rstd * gq.w + bq.w + qq.w;
  *(float4*)(out + base) = o;
}

extern "C" void kernel_launch(void* const* d_in, const int* in_sizes, int n_in,
                              void* d_out, int out_size, void* d_ws, size_t ws_size,
                              hipStream_t stream) {
  (void)in_sizes; (void)n_in; (void)out_size; (void)ws_size;
  const float* query = (const float*)d_in[0];
  const float* key_ = (const float*)d_in[1];
  const float* value = (const float*)d_in[2];
  const float* Wq = (const float*)d_in[3];
  const float* Wk = (const float*)d_in[4];
  const float* Wv = (const float*)d_in[5];
  const float* Wo = (const float*)d_in[6];
  const float* bo = (const float*)d_in[7];
  const float* gamma = (const float*)d_in[8];
  const float* beta = (const float*)d_in[9];
  float* out = (float*)d_out;

  const size_t NELEM = (size_t)M_TOT * 1024;  // 8388608
  uint16_t* wsp = (uint16_t*)d_ws;
  uint16_t* WqT = wsp;                   // 4 x 1M bf16 (Wq,Wk,Wv,Wo contiguous)
  uint16_t* WoT = WqT + 3 * 1024 * 1024;
  uint16_t* xq = WqT + 4 * 1024 * 1024;  // xq,xk,xv contiguous (3 x NELEM)
  uint16_t* qb = xq + 3 * NELEM;         // qb,kb,vt contiguous (z * NELEM)
  uint16_t* attnO = xq;                  // alias: xq dead after QKV-GEMM
  float* proj = (float*)(xq + NELEM);    // alias: xk+xv dead after QKV-GEMM (32MB)

  const int n4 = (int)(NELEM / 4);
  conv_bf16_k<<<dim3(8192, 3), 256, 0, stream>>>(query, key_, value, xq, n4);

  transpose_conv<<<dim3(32, 32, 4), dim3(32, 8), 0, stream>>>(Wq, Wk, Wv, Wo, WqT);

  gemm_bf16<3><<<dim3(8, 64, 3), 256, 0, stream>>>(xq, WqT, qb, nullptr);

  attention_k<<<dim3(N_SEQ / 256, 64), 256, 0, stream>>>(qb, qb + NELEM, qb + 2 * NELEM, attnO);

  gemm_bf16<1><<<dim3(8, 64), 256, 0, stream>>>(attnO, WoT, proj, bo);

  ln_res_k<<<8192, 256, 0, stream>>>(proj, query, gamma, beta, out);
}

// Round 5
// 360.782 us; speedup vs baseline: 1.4976x; 1.0118x over previous
//
#include <hip/hip_runtime.h>
#include <stdint.h>

#define K_DIM 1024
#define B_SZ 4
#define N_SEQ 2048
#define HEADS 16
#define DH 64
#define M_TOT (B_SZ * N_SEQ)  // 8192

typedef __bf16 bf16x8 __attribute__((ext_vector_type(8)));
typedef __bf16 bf16x4 __attribute__((ext_vector_type(4)));
typedef float f32x4 __attribute__((ext_vector_type(4)));
typedef short s16x4 __attribute__((ext_vector_type(4)));

typedef const uint32_t __attribute__((address_space(1))) gas_u32;
typedef uint32_t __attribute__((address_space(3))) las_u32;

#define CE_SCALE 0.1803368801f  // 0.125 * log2(e), folded into Q projection

__device__ __forceinline__ uint16_t f2bf(float f) {
  uint32_t u = __float_as_uint(f);
  u += 0x7FFFu + ((u >> 16) & 1u);  // round-nearest-even
  return (uint16_t)(u >> 16);
}

__device__ __forceinline__ void gld_lds16(const uint16_t* g, uint16_t* lds) {
  __builtin_amdgcn_global_load_lds((gas_u32*)g, (las_u32*)lds, 16, 0, 0);
}

// K=16 bf16 MFMA: A C-layout-compatible (k = (lane>>4)*4 + j).
#if defined(__has_builtin)
#if __has_builtin(__builtin_amdgcn_mfma_f32_16x16x16bf16_1k)
#define HAVE_MFMA16_BUILTIN 1
#endif
#endif

__device__ __forceinline__ f32x4 mfma16(bf16x4 a, bf16x4 b, f32x4 c) {
#ifdef HAVE_MFMA16_BUILTIN
  return __builtin_amdgcn_mfma_f32_16x16x16bf16_1k(
      __builtin_bit_cast(s16x4, a), __builtin_bit_cast(s16x4, b), c, 0, 0, 0);
#else
  f32x4 d;
  asm("v_mfma_f32_16x16x16_bf16 %0, %1, %2, %3"
      : "=v"(d)
      : "v"(a), "v"(b), "v"(c));
  return d;
#endif
}

// ---------------- fp32 -> bf16 convert (batched over 3 tensors) ----------------
__global__ __launch_bounds__(256) void conv_bf16_k(const float* __restrict__ s0,
                                                   const float* __restrict__ s1,
                                                   const float* __restrict__ s2,
                                                   uint16_t* __restrict__ dstbase, int n4) {
  const int z = blockIdx.y;
  const float* src = (z == 0) ? s0 : (z == 1) ? s1 : s2;
  uint16_t* dst = dstbase + (size_t)z * M_TOT * K_DIM;
  int i = blockIdx.x * blockDim.x + threadIdx.x;
  if (i < n4) {
    float4 v = ((const float4*)src)[i];
    ushort4 o;
    o.x = f2bf(v.x); o.y = f2bf(v.y); o.z = f2bf(v.z); o.w = f2bf(v.w);
    ((ushort4*)dst)[i] = o;
  }
}

// ------------- transpose + convert weights (batched over 4) ----------------------
__global__ __launch_bounds__(256) void transpose_conv(const float* __restrict__ s0,
                                                      const float* __restrict__ s1,
                                                      const float* __restrict__ s2,
                                                      const float* __restrict__ s3,
                                                      uint16_t* __restrict__ dstbase) {
  __shared__ float tile[32][33];
  const int z = blockIdx.z;
  const float* src = (z == 0) ? s0 : (z == 1) ? s1 : (z == 2) ? s2 : s3;
  uint16_t* dst = dstbase + (size_t)z * 1024 * 1024;
  const int tx = threadIdx.x, ty = threadIdx.y;
  const int bx = blockIdx.x * 32, by = blockIdx.y * 32;
#pragma unroll
  for (int i = 0; i < 32; i += 8)
    tile[ty + i][tx] = src[(size_t)(by + ty + i) * 1024 + bx + tx];
  __syncthreads();
#pragma unroll
  for (int i = 0; i < 32; i += 8)
    dst[(size_t)(bx + ty + i) * 1024 + by + tx] = f2bf(tile[tx][ty + i]);
}

// ---------------- GEMM: C[M,1024] = A[M,1024] @ B[1024,1024], BT[n][k] given -----
// MODE 3: fused QKV (z=0 Q scaled -> [B,H,N,Dh]; z=1 K -> [B,H,N,Dh]; z=2 V -> [B,H,Dh,N])
// MODE 1: fp32 out row-major + bias (output projection).
template <int MODE>
__global__ __launch_bounds__(256, 2) void gemm_bf16(const uint16_t* __restrict__ A,
                                                    const uint16_t* __restrict__ BT,
                                                    void* __restrict__ Cout,
                                                    const float* __restrict__ bias) {
  __shared__ __align__(16) uint16_t As[128 * 32];
  __shared__ __align__(16) uint16_t Bs[128 * 32];
  const int tid = threadIdx.x;
  const int wave = tid >> 6, lane = tid & 63;
  const int g = lane >> 4, c16 = lane & 15;
  const int m0 = blockIdx.y * 128, n0 = blockIdx.x * 128;
  const int wr = wave >> 1, wc = wave & 1;
  int z = 0;
  float scale = 1.f;
  if (MODE == 3) {
    z = blockIdx.z;
    A += (size_t)z * M_TOT * K_DIM;
    BT += (size_t)z * 1024 * 1024;
    scale = (z == 0) ? CE_SCALE : 1.f;
  }

  const f32x4 fzero = {0.f, 0.f, 0.f, 0.f};
  f32x4 acc[4][4];
#pragma unroll
  for (int i = 0; i < 4; ++i)
#pragma unroll
    for (int j = 0; j < 4; ++j) acc[i][j] = fzero;

  const int srow = wave * 32 + (lane >> 2);
  const int scol = (lane & 3) * 8;
  const uint16_t* ag0 = A + (size_t)(m0 + srow) * K_DIM + scol;
  const uint16_t* ag1 = A + (size_t)(m0 + srow + 16) * K_DIM + scol;
  const uint16_t* bg0 = BT + (size_t)(n0 + srow) * K_DIM + scol;
  const uint16_t* bg1 = BT + (size_t)(n0 + srow + 16) * K_DIM + scol;
  uint16_t* la0 = &As[(wave * 32) * 32];
  uint16_t* la1 = &As[(wave * 32 + 16) * 32];
  uint16_t* lb0 = &Bs[(wave * 32) * 32];
  uint16_t* lb1 = &Bs[(wave * 32 + 16) * 32];

  for (int kt = 0; kt < K_DIM / 32; ++kt) {
    __syncthreads();
    gld_lds16(ag0 + kt * 32, la0);
    gld_lds16(ag1 + kt * 32, la1);
    gld_lds16(bg0 + kt * 32, lb0);
    gld_lds16(bg1 + kt * 32, lb1);
    __syncthreads();
    bf16x8 avec[4], bvec[4];
#pragma unroll
    for (int i = 0; i < 4; ++i)
      avec[i] = *(const bf16x8*)&As[(wr * 64 + i * 16 + c16) * 32 + g * 8];
#pragma unroll
    for (int j = 0; j < 4; ++j)
      bvec[j] = *(const bf16x8*)&Bs[(wc * 64 + j * 16 + c16) * 32 + g * 8];
#pragma unroll
    for (int i = 0; i < 4; ++i)
#pragma unroll
      for (int j = 0; j < 4; ++j)
        acc[i][j] = __builtin_amdgcn_mfma_f32_16x16x32_bf16(avec[i], bvec[j], acc[i][j], 0, 0, 0);
  }

#pragma unroll
  for (int i = 0; i < 4; ++i) {
#pragma unroll
    for (int j = 0; j < 4; ++j) {
      const int col = n0 + wc * 64 + j * 16 + c16;
      if (MODE == 3 && z == 2) {
        const int h = col >> 6, d = col & 63;
        const int row0 = m0 + wr * 64 + i * 16 + g * 4;
        const int b = row0 >> 11, n = row0 & 2047;
        ushort4 o;
        o.x = f2bf(acc[i][j][0]); o.y = f2bf(acc[i][j][1]);
        o.z = f2bf(acc[i][j][2]); o.w = f2bf(acc[i][j][3]);
        *(ushort4*)&((uint16_t*)Cout)[(size_t)2 * M_TOT * 1024 +
                                      (((size_t)(b * HEADS + h)) * DH + d) * N_SEQ + n] = o;
      } else {
#pragma unroll
        for (int r = 0; r < 4; ++r) {
          const int row = m0 + wr * 64 + i * 16 + g * 4 + r;
          if (MODE == 3) {
            const int b = row >> 11, n = row & 2047;
            const int h = col >> 6, d = col & 63;
            ((uint16_t*)Cout)[(size_t)z * M_TOT * 1024 +
                              (((size_t)(b * HEADS + h)) * N_SEQ + n) * DH + d] =
                f2bf(acc[i][j][r] * scale);
          } else {
            ((float*)Cout)[(size_t)row * 1024 + col] = acc[i][j][r] + bias[col];
          }
        }
      }
    }
  }
}

// ---------------- flash attention v5 ----------------
// 256 q/block (64/wave, qc=4), 64-key tiles, grid 512, XOR-swizzled LDS,
// VGPR-prefetch pipeline. PV uses 16x16x16 MFMA: its A-operand layout
// (k = quad*4 + j) EQUALS the S^T C-layout, so exp-packed P registers feed PV
// directly — no P LDS round trip, LDS = 16KB.
__global__ __launch_bounds__(256, 2) void attention_k(const uint16_t* __restrict__ qm,
                                                      const uint16_t* __restrict__ km,
                                                      const uint16_t* __restrict__ vtm,
                                                      uint16_t* __restrict__ om) {
  __shared__ __align__(16) uint16_t Ks[64 * 64];
  __shared__ __align__(16) uint16_t Vs[64 * 64];
  const int tid = threadIdx.x;
  const int wave = tid >> 6, lane = tid & 63;
  const int g = lane >> 4, c16 = lane & 15;
  const int bh = blockIdx.y, b = bh >> 4, h = bh & 15;
  const int q0 = blockIdx.x * 256 + wave * 64;

  const uint16_t* qbase = qm + (size_t)bh * N_SEQ * DH;
  const uint16_t* kbase = km + (size_t)bh * N_SEQ * DH;
  const uint16_t* vbase = vtm + (size_t)bh * DH * N_SEQ;

  // Q as MFMA B-fragments (col = qrow = c16, k = d), straight from global
  bf16x8 qf[4][2];
#pragma unroll
  for (int qc = 0; qc < 4; ++qc) {
    const uint16_t* qp = qbase + (size_t)(q0 + qc * 16 + c16) * DH + g * 8;
    qf[qc][0] = *(const bf16x8*)qp;
    qf[qc][1] = *(const bf16x8*)(qp + 32);
  }

  const f32x4 fz = {0.f, 0.f, 0.f, 0.f};
  f32x4 oacc[4][4];
#pragma unroll
  for (int qc = 0; qc < 4; ++qc)
#pragma unroll
    for (int jt = 0; jt < 4; ++jt) oacc[qc][jt] = fz;
  float l[4] = {0.f, 0.f, 0.f, 0.f};

  const int sw = c16 & 7;  // XOR swizzle key (row&7 == c16&7 for fragment rows)

  const int ch = tid & 7;
  const int krow0 = tid >> 3, krow1 = (256 + tid) >> 3;
  const int kdst0 = krow0 * 64 + ((ch ^ (krow0 & 7)) << 3);
  const int kdst1 = krow1 * 64 + ((ch ^ (krow1 & 7)) << 3);

  uint4 kp0, kp1, vp0, vp1;
  kp0 = *(const uint4*)&kbase[(size_t)tid * 8];
  kp1 = *(const uint4*)&kbase[(size_t)(256 + tid) * 8];
  vp0 = *(const uint4*)&vbase[(size_t)krow0 * N_SEQ + ch * 8];
  vp1 = *(const uint4*)&vbase[(size_t)krow1 * N_SEQ + ch * 8];
  *(uint4*)&Ks[kdst0] = kp0;
  *(uint4*)&Ks[kdst1] = kp1;
  *(uint4*)&Vs[kdst0] = vp0;
  *(uint4*)&Vs[kdst1] = vp1;
  __syncthreads();

  for (int t = 0; t < N_SEQ / 64; ++t) {
    if (t < N_SEQ / 64 - 1) {
      const size_t ko = (size_t)(t + 1) * 4096;
      const int vc = (t + 1) * 64;
      kp0 = *(const uint4*)&kbase[ko + (size_t)tid * 8];
      kp1 = *(const uint4*)&kbase[ko + (size_t)(256 + tid) * 8];
      vp0 = *(const uint4*)&vbase[(size_t)krow0 * N_SEQ + vc + ch * 8];
      vp1 = *(const uint4*)&vbase[(size_t)krow1 * N_SEQ + vc + ch * 8];
    }

#pragma unroll
    for (int kt = 0; kt < 4; ++kt) {
      const int krow = kt * 16 + c16;
      bf16x8 kf0 = *(const bf16x8*)&Ks[krow * 64 + ((g ^ sw) << 3)];
      bf16x8 kf1 = *(const bf16x8*)&Ks[krow * 64 + (((4 + g) ^ sw) << 3)];
      bf16x4 pk[4];
#pragma unroll
      for (int qc = 0; qc < 4; ++qc) {
        f32x4 z = fz;
        z = __builtin_amdgcn_mfma_f32_16x16x32_bf16(kf0, qf[qc][0], z, 0, 0, 0);
        z = __builtin_amdgcn_mfma_f32_16x16x32_bf16(kf1, qf[qc][1], z, 0, 0, 0);
        const float p0 = __builtin_amdgcn_exp2f(z[0]);
        const float p1 = __builtin_amdgcn_exp2f(z[1]);
        const float p2 = __builtin_amdgcn_exp2f(z[2]);
        const float p3 = __builtin_amdgcn_exp2f(z[3]);
        l[qc] += (p0 + p1) + (p2 + p3);
        bf16x4 pq;
        pq[0] = (__bf16)p0; pq[1] = (__bf16)p1; pq[2] = (__bf16)p2; pq[3] = (__bf16)p3;
        pk[qc] = pq;
      }
      // PV: 16 keys (this kt block) via K=16 MFMA; P regs are already A-layout.
#pragma unroll
      for (int jt = 0; jt < 4; ++jt) {
        bf16x4 vb = *(const bf16x4*)&Vs[(jt * 16 + c16) * 64 +
                                        (((kt * 2 + (g >> 1)) ^ sw) << 3) + (g & 1) * 4];
#pragma unroll
        for (int qc = 0; qc < 4; ++qc) oacc[qc][jt] = mfma16(pk[qc], vb, oacc[qc][jt]);
      }
    }

    if (t < N_SEQ / 64 - 1) {
      __syncthreads();
      *(uint4*)&Ks[kdst0] = kp0;
      *(uint4*)&Ks[kdst1] = kp1;
      *(uint4*)&Vs[kdst0] = vp0;
      *(uint4*)&Vs[kdst1] = vp1;
      __syncthreads();
    }
  }

#pragma unroll
  for (int qc = 0; qc < 4; ++qc) {
    l[qc] += __shfl_xor(l[qc], 16);
    l[qc] += __shfl_xor(l[qc], 32);
  }

#pragma unroll
  for (int qc = 0; qc < 4; ++qc) {
#pragma unroll
    for (int r = 0; r < 4; ++r) {
      const float lr = __shfl(l[qc], g * 4 + r, 16);
      const float inv = 1.f / lr;
      const int row = q0 + qc * 16 + g * 4 + r;
      const size_t base = ((size_t)b * N_SEQ + row) * 1024 + h * 64;
#pragma unroll
      for (int jt = 0; jt < 4; ++jt)
        om[base + jt * 16 + c16] = f2bf(oacc[qc][jt][r] * inv);
    }
  }
}

// ---------------- LayerNorm + residual ----------------
__global__ __launch_bounds__(256) void ln_res_k(const float* __restrict__ proj,
                                                const float* __restrict__ query,
                                                const float* __restrict__ gamma,
                                                const float* __restrict__ beta,
                                                float* __restrict__ out) {
  const int row = blockIdx.x;
  const int tid = threadIdx.x;
  const size_t base = (size_t)row * 1024 + tid * 4;
  float4 v = *(const float4*)(proj + base);
  float s = v.x + v.y + v.z + v.w;
  float s2 = v.x * v.x + v.y * v.y + v.z * v.z + v.w * v.w;
#pragma unroll
  for (int off = 1; off < 64; off <<= 1) {
    s += __shfl_xor(s, off);
    s2 += __shfl_xor(s2, off);
  }
  __shared__ float red[8];
  const int wave = tid >> 6, lane = tid & 63;
  if (lane == 0) { red[wave] = s; red[4 + wave] = s2; }
  __syncthreads();
  s = red[0] + red[1] + red[2] + red[3];
  s2 = red[4] + red[5] + red[6] + red[7];
  const float mu = s * (1.f / 1024.f);
  const float var = fmaxf(s2 * (1.f / 1024.f) - mu * mu, 0.f);
  const float rstd = rsqrtf(var + 1e-5f);
  float4 gq = *(const float4*)(gamma + tid * 4);
  float4 bq = *(const float4*)(beta + tid * 4);
  float4 qq = *(const float4*)(query + base);
  float4 o;
  o.x = (v.x - mu) * rstd * gq.x + bq.x + qq.x;
  o.y = (v.y - mu) * rstd * gq.y + bq.y + qq.y;
  o.z = (v.z - mu) * rstd * gq.z + bq.z + qq.z;
  o.w = (v.w - mu) * rstd * gq.w + bq.w + qq.w;
  *(float4*)(out + base) = o;
}

extern "C" void kernel_launch(void* const* d_in, const int* in_sizes, int n_in,
                              void* d_out, int out_size, void* d_ws, size_t ws_size,
                              hipStream_t stream) {
  (void)in_sizes; (void)n_in; (void)out_size; (void)ws_size;
  const float* query = (const float*)d_in[0];
  const float* key_ = (const float*)d_in[1];
  const float* value = (const float*)d_in[2];
  const float* Wq = (const float*)d_in[3];
  const float* Wk = (const float*)d_in[4];
  const float* Wv = (const float*)d_in[5];
  const float* Wo = (const float*)d_in[6];
  const float* bo = (const float*)d_in[7];
  const float* gamma = (const float*)d_in[8];
  const float* beta = (const float*)d_in[9];
  float* out = (float*)d_out;

  const size_t NELEM = (size_t)M_TOT * 1024;  // 8388608
  uint16_t* wsp = (uint16_t*)d_ws;
  uint16_t* WqT = wsp;                   // 4 x 1M bf16 (Wq,Wk,Wv,Wo contiguous)
  uint16_t* WoT = WqT + 3 * 1024 * 1024;
  uint16_t* xq = WqT + 4 * 1024 * 1024;  // xq,xk,xv contiguous (3 x NELEM)
  uint16_t* qb = xq + 3 * NELEM;         // qb,kb,vt contiguous (z * NELEM)
  uint16_t* attnO = xq;                  // alias: xq dead after QKV-GEMM
  float* proj = (float*)(xq + NELEM);    // alias: xk+xv dead after QKV-GEMM (32MB)

  const int n4 = (int)(NELEM / 4);
  conv_bf16_k<<<dim3(8192, 3), 256, 0, stream>>>(query, key_, value, xq, n4);

  transpose_conv<<<dim3(32, 32, 4), dim3(32, 8), 0, stream>>>(Wq, Wk, Wv, Wo, WqT);

  gemm_bf16<3><<<dim3(8, 64, 3), 256, 0, stream>>>(xq, WqT, qb, nullptr);

  attention_k<<<dim3(N_SEQ / 256, 64), 256, 0, stream>>>(qb, qb + NELEM, qb + 2 * NELEM, attnO);

  gemm_bf16<1><<<dim3(8, 64), 256, 0, stream>>>(attnO, WoT, proj, bo);

  ln_res_k<<<8192, 256, 0, stream>>>(proj, query, gamma, beta, out);
}

// Round 6
// 351.704 us; speedup vs baseline: 1.5362x; 1.0258x over previous
//
#include <hip/hip_runtime.h>
#include <stdint.h>

#define K_DIM 1024
#define B_SZ 4
#define N_SEQ 2048
#define HEADS 16
#define DH 64
#define M_TOT (B_SZ * N_SEQ)  // 8192

typedef __bf16 bf16x8 __attribute__((ext_vector_type(8)));
typedef __bf16 bf16x4 __attribute__((ext_vector_type(4)));
typedef float f32x4 __attribute__((ext_vector_type(4)));
typedef short s16x4 __attribute__((ext_vector_type(4)));

typedef const uint32_t __attribute__((address_space(1))) gas_u32;
typedef uint32_t __attribute__((address_space(3))) las_u32;

#define CE_SCALE 0.1803368801f  // 0.125 * log2(e), folded into Q projection

__device__ __forceinline__ uint16_t f2bf(float f) {
  uint32_t u = __float_as_uint(f);
  u += 0x7FFFu + ((u >> 16) & 1u);  // round-nearest-even
  return (uint16_t)(u >> 16);
}

__device__ __forceinline__ void gld_lds16(const uint16_t* g, uint16_t* lds) {
  __builtin_amdgcn_global_load_lds((gas_u32*)g, (las_u32*)lds, 16, 0, 0);
}

// K=16 bf16 MFMA: A-operand layout (k = quad*4 + j) == our S^T C-layout.
#if defined(__has_builtin)
#if __has_builtin(__builtin_amdgcn_mfma_f32_16x16x16bf16_1k)
#define HAVE_MFMA16_BUILTIN 1
#endif
#endif

__device__ __forceinline__ f32x4 mfma16(bf16x4 a, bf16x4 b, f32x4 c) {
#ifdef HAVE_MFMA16_BUILTIN
  return __builtin_amdgcn_mfma_f32_16x16x16bf16_1k(
      __builtin_bit_cast(s16x4, a), __builtin_bit_cast(s16x4, b), c, 0, 0, 0);
#else
  f32x4 d;
  asm("v_mfma_f32_16x16x16_bf16 %0, %1, %2, %3"
      : "=v"(d)
      : "v"(a), "v"(b), "v"(c));
  return d;
#endif
}

// ---------------- fp32 -> bf16 convert (batched over 3 tensors) ----------------
__global__ __launch_bounds__(256) void conv_bf16_k(const float* __restrict__ s0,
                                                   const float* __restrict__ s1,
                                                   const float* __restrict__ s2,
                                                   uint16_t* __restrict__ dstbase, int n4) {
  const int z = blockIdx.y;
  const float* src = (z == 0) ? s0 : (z == 1) ? s1 : s2;
  uint16_t* dst = dstbase + (size_t)z * M_TOT * K_DIM;
  int i = blockIdx.x * blockDim.x + threadIdx.x;
  if (i < n4) {
    float4 v = ((const float4*)src)[i];
    ushort4 o;
    o.x = f2bf(v.x); o.y = f2bf(v.y); o.z = f2bf(v.z); o.w = f2bf(v.w);
    ((ushort4*)dst)[i] = o;
  }
}

// ------------- transpose + convert weights (batched over 4) ----------------------
__global__ __launch_bounds__(256) void transpose_conv(const float* __restrict__ s0,
                                                      const float* __restrict__ s1,
                                                      const float* __restrict__ s2,
                                                      const float* __restrict__ s3,
                                                      uint16_t* __restrict__ dstbase) {
  __shared__ float tile[32][33];
  const int z = blockIdx.z;
  const float* src = (z == 0) ? s0 : (z == 1) ? s1 : (z == 2) ? s2 : s3;
  uint16_t* dst = dstbase + (size_t)z * 1024 * 1024;
  const int tx = threadIdx.x, ty = threadIdx.y;
  const int bx = blockIdx.x * 32, by = blockIdx.y * 32;
#pragma unroll
  for (int i = 0; i < 32; i += 8)
    tile[ty + i][tx] = src[(size_t)(by + ty + i) * 1024 + bx + tx];
  __syncthreads();
#pragma unroll
  for (int i = 0; i < 32; i += 8)
    dst[(size_t)(bx + ty + i) * 1024 + by + tx] = f2bf(tile[tx][ty + i]);
}

// ---------------- GEMM: C[M,1024] = A[M,1024] @ B[1024,1024], BT[n][k] given -----
// XCD-locality swizzle: flat 1-D grid; XCD (bid&7) owns m-tiles [xcd*8, xcd*8+8),
// n fastest, z slowest -> per-XCD working set (A-slice 2MB + B 2MB) fits one L2.
// MODE 3: fused QKV (z=0 Q scaled -> [B,H,N,Dh]; z=1 K -> [B,H,N,Dh]; z=2 V -> [B,H,Dh,N])
// MODE 1: fp32 out row-major + bias (output projection), z=0 only.
template <int MODE>
__global__ __launch_bounds__(256, 2) void gemm_bf16(const uint16_t* __restrict__ A,
                                                    const uint16_t* __restrict__ BT,
                                                    void* __restrict__ Cout,
                                                    const float* __restrict__ bias) {
  __shared__ __align__(16) uint16_t As[128 * 32];
  __shared__ __align__(16) uint16_t Bs[128 * 32];
  const int tid = threadIdx.x;
  const int wave = tid >> 6, lane = tid & 63;
  const int g = lane >> 4, c16 = lane & 15;

  // swizzled block mapping
  const int bid = blockIdx.x;
  const int xcd = bid & 7;
  const int l = bid >> 3;
  const int z = (MODE == 3) ? (l >> 6) : 0;
  const int r = l & 63;
  const int n0 = (r & 7) * 128;
  const int m0 = (xcd * 8 + (r >> 3)) * 128;

  const int wr = wave >> 1, wc = wave & 1;
  float scale = 1.f;
  if (MODE == 3) {
    A += (size_t)z * M_TOT * K_DIM;
    BT += (size_t)z * 1024 * 1024;
    scale = (z == 0) ? CE_SCALE : 1.f;
  }

  const f32x4 fzero = {0.f, 0.f, 0.f, 0.f};
  f32x4 acc[4][4];
#pragma unroll
  for (int i = 0; i < 4; ++i)
#pragma unroll
    for (int j = 0; j < 4; ++j) acc[i][j] = fzero;

  const int srow = wave * 32 + (lane >> 2);
  const int scol = (lane & 3) * 8;
  const uint16_t* ag0 = A + (size_t)(m0 + srow) * K_DIM + scol;
  const uint16_t* ag1 = A + (size_t)(m0 + srow + 16) * K_DIM + scol;
  const uint16_t* bg0 = BT + (size_t)(n0 + srow) * K_DIM + scol;
  const uint16_t* bg1 = BT + (size_t)(n0 + srow + 16) * K_DIM + scol;
  uint16_t* la0 = &As[(wave * 32) * 32];
  uint16_t* la1 = &As[(wave * 32 + 16) * 32];
  uint16_t* lb0 = &Bs[(wave * 32) * 32];
  uint16_t* lb1 = &Bs[(wave * 32 + 16) * 32];

  for (int kt = 0; kt < K_DIM / 32; ++kt) {
    __syncthreads();
    gld_lds16(ag0 + kt * 32, la0);
    gld_lds16(ag1 + kt * 32, la1);
    gld_lds16(bg0 + kt * 32, lb0);
    gld_lds16(bg1 + kt * 32, lb1);
    __syncthreads();
    bf16x8 avec[4], bvec[4];
#pragma unroll
    for (int i = 0; i < 4; ++i)
      avec[i] = *(const bf16x8*)&As[(wr * 64 + i * 16 + c16) * 32 + g * 8];
#pragma unroll
    for (int j = 0; j < 4; ++j)
      bvec[j] = *(const bf16x8*)&Bs[(wc * 64 + j * 16 + c16) * 32 + g * 8];
#pragma unroll
    for (int i = 0; i < 4; ++i)
#pragma unroll
      for (int j = 0; j < 4; ++j)
        acc[i][j] = __builtin_amdgcn_mfma_f32_16x16x32_bf16(avec[i], bvec[j], acc[i][j], 0, 0, 0);
  }

#pragma unroll
  for (int i = 0; i < 4; ++i) {
#pragma unroll
    for (int j = 0; j < 4; ++j) {
      const int col = n0 + wc * 64 + j * 16 + c16;
      if (MODE == 3 && z == 2) {
        const int h = col >> 6, d = col & 63;
        const int row0 = m0 + wr * 64 + i * 16 + g * 4;
        const int b = row0 >> 11, n = row0 & 2047;
        ushort4 o;
        o.x = f2bf(acc[i][j][0]); o.y = f2bf(acc[i][j][1]);
        o.z = f2bf(acc[i][j][2]); o.w = f2bf(acc[i][j][3]);
        *(ushort4*)&((uint16_t*)Cout)[(size_t)2 * M_TOT * 1024 +
                                      (((size_t)(b * HEADS + h)) * DH + d) * N_SEQ + n] = o;
      } else {
#pragma unroll
        for (int r2 = 0; r2 < 4; ++r2) {
          const int row = m0 + wr * 64 + i * 16 + g * 4 + r2;
          if (MODE == 3) {
            const int b = row >> 11, n = row & 2047;
            const int h = col >> 6, d = col & 63;
            ((uint16_t*)Cout)[(size_t)z * M_TOT * 1024 +
                              (((size_t)(b * HEADS + h)) * N_SEQ + n) * DH + d] =
                f2bf(acc[i][j][r2] * scale);
          } else {
            ((float*)Cout)[(size_t)row * 1024 + col] = acc[i][j][r2] + bias[col];
          }
        }
      }
    }
  }
}

// ---------------- flash attention v6 ----------------
// 256 q/block (64/wave, qc=4), 64-key tiles, XOR-swizzled LDS, VGPR-prefetch
// pipeline, PV via K=16 MFMA straight from exp-packed registers (no P LDS).
// XCD-locality swizzle: XCD (bid&7) owns bh in [xcd*8, xcd*8+8) -> its K/V
// (4 MB) stays resident in that XCD's L2 across all 8 q-blocks.
__global__ __launch_bounds__(256, 2) void attention_k(const uint16_t* __restrict__ qm,
                                                      const uint16_t* __restrict__ km,
                                                      const uint16_t* __restrict__ vtm,
                                                      uint16_t* __restrict__ om) {
  __shared__ __align__(16) uint16_t Ks[64 * 64];
  __shared__ __align__(16) uint16_t Vs[64 * 64];
  const int tid = threadIdx.x;
  const int wave = tid >> 6, lane = tid & 63;
  const int g = lane >> 4, c16 = lane & 15;

  const int bid = blockIdx.x;
  const int xcd = bid & 7;
  const int l0 = bid >> 3;
  const int bh = xcd * 8 + (l0 & 7);
  const int qblk = l0 >> 3;
  const int b = bh >> 4, h = bh & 15;
  const int q0 = qblk * 256 + wave * 64;

  const uint16_t* qbase = qm + (size_t)bh * N_SEQ * DH;
  const uint16_t* kbase = km + (size_t)bh * N_SEQ * DH;
  const uint16_t* vbase = vtm + (size_t)bh * DH * N_SEQ;

  // Q as MFMA B-fragments (col = qrow = c16, k = d), straight from global
  bf16x8 qf[4][2];
#pragma unroll
  for (int qc = 0; qc < 4; ++qc) {
    const uint16_t* qp = qbase + (size_t)(q0 + qc * 16 + c16) * DH + g * 8;
    qf[qc][0] = *(const bf16x8*)qp;
    qf[qc][1] = *(const bf16x8*)(qp + 32);
  }

  const f32x4 fz = {0.f, 0.f, 0.f, 0.f};
  f32x4 oacc[4][4];
#pragma unroll
  for (int qc = 0; qc < 4; ++qc)
#pragma unroll
    for (int jt = 0; jt < 4; ++jt) oacc[qc][jt] = fz;
  float l[4] = {0.f, 0.f, 0.f, 0.f};

  const int sw = c16 & 7;  // XOR swizzle key (row&7 == c16&7 for fragment rows)

  const int ch = tid & 7;
  const int krow0 = tid >> 3, krow1 = (256 + tid) >> 3;
  const int kdst0 = krow0 * 64 + ((ch ^ (krow0 & 7)) << 3);
  const int kdst1 = krow1 * 64 + ((ch ^ (krow1 & 7)) << 3);

  uint4 kp0, kp1, vp0, vp1;
  kp0 = *(const uint4*)&kbase[(size_t)tid * 8];
  kp1 = *(const uint4*)&kbase[(size_t)(256 + tid) * 8];
  vp0 = *(const uint4*)&vbase[(size_t)krow0 * N_SEQ + ch * 8];
  vp1 = *(const uint4*)&vbase[(size_t)krow1 * N_SEQ + ch * 8];
  *(uint4*)&Ks[kdst0] = kp0;
  *(uint4*)&Ks[kdst1] = kp1;
  *(uint4*)&Vs[kdst0] = vp0;
  *(uint4*)&Vs[kdst1] = vp1;
  __syncthreads();

  for (int t = 0; t < N_SEQ / 64; ++t) {
    if (t < N_SEQ / 64 - 1) {
      const size_t ko = (size_t)(t + 1) * 4096;
      const int vc = (t + 1) * 64;
      kp0 = *(const uint4*)&kbase[ko + (size_t)tid * 8];
      kp1 = *(const uint4*)&kbase[ko + (size_t)(256 + tid) * 8];
      vp0 = *(const uint4*)&vbase[(size_t)krow0 * N_SEQ + vc + ch * 8];
      vp1 = *(const uint4*)&vbase[(size_t)krow1 * N_SEQ + vc + ch * 8];
    }

#pragma unroll
    for (int kt = 0; kt < 4; ++kt) {
      const int krow = kt * 16 + c16;
      bf16x8 kf0 = *(const bf16x8*)&Ks[krow * 64 + ((g ^ sw) << 3)];
      bf16x8 kf1 = *(const bf16x8*)&Ks[krow * 64 + (((4 + g) ^ sw) << 3)];
      bf16x4 pk[4];
#pragma unroll
      for (int qc = 0; qc < 4; ++qc) {
        f32x4 z = fz;
        z = __builtin_amdgcn_mfma_f32_16x16x32_bf16(kf0, qf[qc][0], z, 0, 0, 0);
        z = __builtin_amdgcn_mfma_f32_16x16x32_bf16(kf1, qf[qc][1], z, 0, 0, 0);
        const float p0 = __builtin_amdgcn_exp2f(z[0]);
        const float p1 = __builtin_amdgcn_exp2f(z[1]);
        const float p2 = __builtin_amdgcn_exp2f(z[2]);
        const float p3 = __builtin_amdgcn_exp2f(z[3]);
        l[qc] += (p0 + p1) + (p2 + p3);
        bf16x4 pq;
        pq[0] = (__bf16)p0; pq[1] = (__bf16)p1; pq[2] = (__bf16)p2; pq[3] = (__bf16)p3;
        pk[qc] = pq;
      }
      // PV: 16 keys (this kt block) via K=16 MFMA; P regs are already A-layout.
#pragma unroll
      for (int jt = 0; jt < 4; ++jt) {
        bf16x4 vb = *(const bf16x4*)&Vs[(jt * 16 + c16) * 64 +
                                        (((kt * 2 + (g >> 1)) ^ sw) << 3) + (g & 1) * 4];
#pragma unroll
        for (int qc = 0; qc < 4; ++qc) oacc[qc][jt] = mfma16(pk[qc], vb, oacc[qc][jt]);
      }
    }

    if (t < N_SEQ / 64 - 1) {
      __syncthreads();
      *(uint4*)&Ks[kdst0] = kp0;
      *(uint4*)&Ks[kdst1] = kp1;
      *(uint4*)&Vs[kdst0] = vp0;
      *(uint4*)&Vs[kdst1] = vp1;
      __syncthreads();
    }
  }

#pragma unroll
  for (int qc = 0; qc < 4; ++qc) {
    l[qc] += __shfl_xor(l[qc], 16);
    l[qc] += __shfl_xor(l[qc], 32);
  }

#pragma unroll
  for (int qc = 0; qc < 4; ++qc) {
#pragma unroll
    for (int r = 0; r < 4; ++r) {
      const float lr = __shfl(l[qc], g * 4 + r, 16);
      const float inv = 1.f / lr;
      const int row = q0 + qc * 16 + g * 4 + r;
      const size_t base = ((size_t)b * N_SEQ + row) * 1024 + h * 64;
#pragma unroll
      for (int jt = 0; jt < 4; ++jt)
        om[base + jt * 16 + c16] = f2bf(oacc[qc][jt][r] * inv);
    }
  }
}

// ---------------- LayerNorm + residual ----------------
__global__ __launch_bounds__(256) void ln_res_k(const float* __restrict__ proj,
                                                const float* __restrict__ query,
                                                const float* __restrict__ gamma,
                                                const float* __restrict__ beta,
                                                float* __restrict__ out) {
  const int row = blockIdx.x;
  const int tid = threadIdx.x;
  const size_t base = (size_t)row * 1024 + tid * 4;
  float4 v = *(const float4*)(proj + base);
  float s = v.x + v.y + v.z + v.w;
  float s2 = v.x * v.x + v.y * v.y + v.z * v.z + v.w * v.w;
#pragma unroll
  for (int off = 1; off < 64; off <<= 1) {
    s += __shfl_xor(s, off);
    s2 += __shfl_xor(s2, off);
  }
  __shared__ float red[8];
  const int wave = tid >> 6, lane = tid & 63;
  if (lane == 0) { red[wave] = s; red[4 + wave] = s2; }
  __syncthreads();
  s = red[0] + red[1] + red[2] + red[3];
  s2 = red[4] + red[5] + red[6] + red[7];
  const float mu = s * (1.f / 1024.f);
  const float var = fmaxf(s2 * (1.f / 1024.f) - mu * mu, 0.f);
  const float rstd = rsqrtf(var + 1e-5f);
  float4 gq = *(const float4*)(gamma + tid * 4);
  float4 bq = *(const float4*)(beta + tid * 4);
  float4 qq = *(const float4*)(query + base);
  float4 o;
  o.x = (v.x - mu) * rstd * gq.x + bq.x + qq.x;
  o.y = (v.y - mu) * rstd * gq.y + bq.y + qq.y;
  o.z = (v.z - mu) * rstd * gq.z + bq.z + qq.z;
  o.w = (v.w - mu) * rstd * gq.w + bq.w + qq.w;
  *(float4*)(out + base) = o;
}

extern "C" void kernel_launch(void* const* d_in, const int* in_sizes, int n_in,
                              void* d_out, int out_size, void* d_ws, size_t ws_size,
                              hipStream_t stream) {
  (void)in_sizes; (void)n_in; (void)out_size; (void)ws_size;
  const float* query = (const float*)d_in[0];
  const float* key_ = (const float*)d_in[1];
  const float* value = (const float*)d_in[2];
  const float* Wq = (const float*)d_in[3];
  const float* Wk = (const float*)d_in[4];
  const float* Wv = (const float*)d_in[5];
  const float* Wo = (const float*)d_in[6];
  const float* bo = (const float*)d_in[7];
  const float* gamma = (const float*)d_in[8];
  const float* beta = (const float*)d_in[9];
  float* out = (float*)d_out;

  const size_t NELEM = (size_t)M_TOT * 1024;  // 8388608
  uint16_t* wsp = (uint16_t*)d_ws;
  uint16_t* WqT = wsp;                   // 4 x 1M bf16 (Wq,Wk,Wv,Wo contiguous)
  uint16_t* WoT = WqT + 3 * 1024 * 1024;
  uint16_t* xq = WqT + 4 * 1024 * 1024;  // xq,xk,xv contiguous (3 x NELEM)
  uint16_t* qb = xq + 3 * NELEM;         // qb,kb,vt contiguous (z * NELEM)
  uint16_t* attnO = xq;                  // alias: xq dead after QKV-GEMM
  float* proj = (float*)(xq + NELEM);    // alias: xk+xv dead after QKV-GEMM (32MB)

  const int n4 = (int)(NELEM / 4);
  conv_bf16_k<<<dim3(8192, 3), 256, 0, stream>>>(query, key_, value, xq, n4);

  transpose_conv<<<dim3(32, 32, 4), dim3(32, 8), 0, stream>>>(Wq, Wk, Wv, Wo, WqT);

  gemm_bf16<3><<<1536, 256, 0, stream>>>(xq, WqT, qb, nullptr);

  attention_k<<<512, 256, 0, stream>>>(qb, qb + NELEM, qb + 2 * NELEM, attnO);

  gemm_bf16<1><<<512, 256, 0, stream>>>(attnO, WoT, proj, bo);

  ln_res_k<<<8192, 256, 0, stream>>>(proj, query, gamma, beta, out);
}